// Round 1
// baseline (982.863 us; speedup 1.0000x reference)
//
#include <hip/hip_runtime.h>

// GCNEncoder: 2x GCNConv (+self-loops, sym-norm) + ReLU, then global mean pool.
// Fixed problem sizes from the reference.
constexpr int N_NODES  = 50000;
constexpr int N_EDGES  = 800000;
constexpr int N_GRAPHS = 256;
constexpr int IN_DIM   = 128;
constexpr int HID      = 64;
constexpr int EMB      = 128;

// Workspace layout (float offsets). agg2 aliases h1_pre+agg1 (dead after gemm2).
constexpr size_t OFF_DEG  = 0;                       // 50000
constexpr size_t OFF_DIS  = OFF_DEG + N_NODES;       // 50000
constexpr size_t OFF_POOL = OFF_DIS + N_NODES;       // 256*128
constexpr size_t OFF_CNT  = OFF_POOL + (size_t)N_GRAPHS * EMB; // 256
constexpr size_t OFF_H1P  = 133120;                  // 50000*64  (aligned start)
constexpr size_t OFF_AGG1 = OFF_H1P + (size_t)N_NODES * HID;   // 50000*64
constexpr size_t OFF_H2P  = OFF_AGG1 + (size_t)N_NODES * HID;  // 50000*128
constexpr size_t OFF_AGG2 = OFF_H1P;                 // aliases h1_pre+agg1, 50000*128

__global__ void k_init_deg(float* __restrict__ deg) {
    int i = blockIdx.x * blockDim.x + threadIdx.x;
    if (i < N_NODES) deg[i] = 1.0f;   // self-loop weight 1
}

__global__ void k_deg_accum(const int* __restrict__ dst, const float* __restrict__ ew,
                            float* __restrict__ deg) {
    int e = blockIdx.x * blockDim.x + threadIdx.x;
    if (e < N_EDGES) atomicAdd(&deg[dst[e]], ew[e]);
}

__global__ void k_dis(const float* __restrict__ deg, float* __restrict__ dis) {
    int i = blockIdx.x * blockDim.x + threadIdx.x;
    if (i < N_NODES) {
        float d = deg[i];
        dis[i] = d > 0.f ? rsqrtf(d) : 0.f;
    }
}

// h1_pre = x @ W1 : [N,128] x [128,64]. Block = 256 thr = 4 nodes x 64 cols.
__global__ __launch_bounds__(256) void k_gemm1(const float* __restrict__ x,
                                               const float* __restrict__ W1,
                                               float* __restrict__ h) {
    __shared__ float Ws[IN_DIM * HID];   // 32 KB
    __shared__ float xs[4][IN_DIM];
    int tid = threadIdx.x;
    for (int i = tid; i < IN_DIM * HID; i += 256) Ws[i] = W1[i];
    int base = blockIdx.x * 4;
    for (int i = tid; i < 4 * IN_DIM; i += 256) {
        int ln = i >> 7, k = i & 127;
        int node = base + ln;
        xs[ln][k] = (node < N_NODES) ? x[(size_t)node * IN_DIM + k] : 0.f;
    }
    __syncthreads();
    int ln = tid >> 6, j = tid & 63;
    int node = base + ln;
    float acc = 0.f;
    #pragma unroll 8
    for (int k = 0; k < IN_DIM; ++k) acc += xs[ln][k] * Ws[k * HID + j];
    if (node < N_NODES) h[(size_t)node * HID + j] = acc;
}

// agg1[dst][j] += h1_pre[src][j] * dis[src]*w*dis[dst].  Block = 4 edges x 64.
__global__ __launch_bounds__(256) void k_scatter1(const int* __restrict__ src,
                                                  const int* __restrict__ dst,
                                                  const float* __restrict__ ew,
                                                  const float* __restrict__ dis,
                                                  const float* __restrict__ h,
                                                  float* __restrict__ agg) {
    int idx = blockIdx.x * 256 + threadIdx.x;
    int e = idx >> 6, j = idx & 63;
    if (e >= N_EDGES) return;
    int s = src[e], d = dst[e];
    float norm = dis[s] * ew[e] * dis[d];
    atomicAdd(&agg[(size_t)d * HID + j], h[(size_t)s * HID + j] * norm);
}

// In-place: agg1 = relu(agg1 + h1_pre/deg + b1)
__global__ void k_bias_relu1(float* __restrict__ agg, const float* __restrict__ h1p,
                             const float* __restrict__ dis, const float* __restrict__ b1) {
    int idx = blockIdx.x * blockDim.x + threadIdx.x;
    if (idx >= N_NODES * HID) return;
    int i = idx >> 6, j = idx & 63;
    float di = dis[i];
    float v = agg[idx] + h1p[idx] * di * di + b1[j];
    agg[idx] = v > 0.f ? v : 0.f;
}

// h2_pre = h1 @ W2 : [N,64] x [64,128]. Block = 256 thr = 2 nodes x 128 cols.
__global__ __launch_bounds__(256) void k_gemm2(const float* __restrict__ h1,
                                               const float* __restrict__ W2,
                                               float* __restrict__ h) {
    __shared__ float Ws[HID * EMB];   // 32 KB
    __shared__ float xs[2][HID];
    int tid = threadIdx.x;
    for (int i = tid; i < HID * EMB; i += 256) Ws[i] = W2[i];
    int base = blockIdx.x * 2;
    for (int i = tid; i < 2 * HID; i += 256) {
        int ln = i >> 6, k = i & 63;
        int node = base + ln;
        xs[ln][k] = (node < N_NODES) ? h1[(size_t)node * HID + k] : 0.f;
    }
    __syncthreads();
    int ln = tid >> 7, j = tid & 127;
    int node = base + ln;
    float acc = 0.f;
    #pragma unroll 8
    for (int k = 0; k < HID; ++k) acc += xs[ln][k] * Ws[k * EMB + j];
    if (node < N_NODES) h[(size_t)node * EMB + j] = acc;
}

// agg2[dst][j] += h2_pre[src][j] * norm.  Block = 2 edges x 128.
__global__ __launch_bounds__(256) void k_scatter2(const int* __restrict__ src,
                                                  const int* __restrict__ dst,
                                                  const float* __restrict__ ew,
                                                  const float* __restrict__ dis,
                                                  const float* __restrict__ h,
                                                  float* __restrict__ agg) {
    int idx = blockIdx.x * 256 + threadIdx.x;
    int e = idx >> 7, j = idx & 127;
    if (e >= N_EDGES) return;
    int s = src[e], d = dst[e];
    float norm = dis[s] * ew[e] * dis[d];
    atomicAdd(&agg[(size_t)d * EMB + j], h[(size_t)s * EMB + j] * norm);
}

// v = relu(agg2 + h2_pre/deg + b2); pool[batch[i]] += v; cnt[batch[i]] += 1.
__global__ __launch_bounds__(256) void k_final_pool(const float* __restrict__ agg2,
                                                    const float* __restrict__ h2p,
                                                    const float* __restrict__ dis,
                                                    const float* __restrict__ b2,
                                                    const int* __restrict__ batch,
                                                    float* __restrict__ pool,
                                                    float* __restrict__ cnt) {
    int idx = blockIdx.x * 256 + threadIdx.x;
    int node = idx >> 7, j = idx & 127;
    if (node >= N_NODES) return;
    float di = dis[node];
    float v = agg2[idx] + h2p[idx] * di * di + b2[j];
    v = v > 0.f ? v : 0.f;
    int g = batch[node];
    atomicAdd(&pool[(size_t)g * EMB + j], v);
    if (j == 0) atomicAdd(&cnt[g], 1.0f);
}

__global__ void k_divide(const float* __restrict__ pool, const float* __restrict__ cnt,
                         float* __restrict__ out) {
    int idx = blockIdx.x * blockDim.x + threadIdx.x;
    if (idx >= N_GRAPHS * EMB) return;
    float c = cnt[idx >> 7];
    out[idx] = pool[idx] / fmaxf(c, 1.0f);
}

extern "C" void kernel_launch(void* const* d_in, const int* in_sizes, int n_in,
                              void* d_out, int out_size, void* d_ws, size_t ws_size,
                              hipStream_t stream) {
    const float* x     = (const float*)d_in[0];
    const int*   eidx  = (const int*)d_in[1];     // [2, E]: src then dst
    const float* ew    = (const float*)d_in[2];
    const int*   batch = (const int*)d_in[3];
    const float* W1    = (const float*)d_in[4];
    const float* b1    = (const float*)d_in[5];
    const float* W2    = (const float*)d_in[6];
    const float* b2    = (const float*)d_in[7];
    float* out = (float*)d_out;

    const int* src = eidx;
    const int* dst = eidx + N_EDGES;

    float* ws   = (float*)d_ws;
    float* deg  = ws + OFF_DEG;
    float* dis  = ws + OFF_DIS;
    float* pool = ws + OFF_POOL;
    float* cnt  = ws + OFF_CNT;
    float* h1p  = ws + OFF_H1P;
    float* agg1 = ws + OFF_AGG1;
    float* h2p  = ws + OFF_H2P;
    float* agg2 = ws + OFF_AGG2;   // aliases h1p+agg1 (dead after gemm2)

    // Zero accumulators that are live first.
    hipMemsetAsync(agg1, 0, (size_t)N_NODES * HID * sizeof(float), stream);
    hipMemsetAsync(pool, 0, ((size_t)N_GRAPHS * EMB + N_GRAPHS) * sizeof(float), stream);

    // Degree + normalization.
    k_init_deg<<<(N_NODES + 255) / 256, 256, 0, stream>>>(deg);
    k_deg_accum<<<(N_EDGES + 255) / 256, 256, 0, stream>>>(dst, ew, deg);
    k_dis<<<(N_NODES + 255) / 256, 256, 0, stream>>>(deg, dis);

    // Layer 1.
    k_gemm1<<<(N_NODES + 3) / 4, 256, 0, stream>>>(x, W1, h1p);
    k_scatter1<<<(N_EDGES * 64 + 255) / 256, 256, 0, stream>>>(src, dst, ew, dis, h1p, agg1);
    k_bias_relu1<<<(N_NODES * HID + 255) / 256, 256, 0, stream>>>(agg1, h1p, dis, b1);

    // Layer 2 (h1 lives in agg1).
    k_gemm2<<<(N_NODES + 1) / 2, 256, 0, stream>>>(agg1, W2, h2p);
    // agg2 aliases h1p+agg1 — safe to zero only after gemm2 consumed h1.
    hipMemsetAsync(agg2, 0, (size_t)N_NODES * EMB * sizeof(float), stream);
    k_scatter2<<<(N_EDGES * 128 + 255) / 256, 256, 0, stream>>>(src, dst, ew, dis, h2p, agg2);

    // Fused relu + mean-pool accumulate, then divide.
    k_final_pool<<<(N_NODES * 128 + 255) / 256, 256, 0, stream>>>(agg2, h2p, dis, b2, batch, pool, cnt);
    k_divide<<<(N_GRAPHS * EMB + 255) / 256, 256, 0, stream>>>(pool, cnt, out);
}

// Round 2
// 632.252 us; speedup vs baseline: 1.5545x; 1.5545x over previous
//
#include <hip/hip_runtime.h>

// GCNEncoder: 2x GCNConv (+self-loops, sym-norm) + ReLU, then global mean pool.
// Round 2: CSR-by-dst counting sort built per call; gather-form aggregation
// (no float atomics on the big tensors). Pool fused into gather2 epilogue.
constexpr int N_NODES  = 50000;
constexpr int N_EDGES  = 800000;
constexpr int N_GRAPHS = 256;
constexpr int IN_DIM   = 128;
constexpr int HID      = 64;
constexpr int EMB      = 128;
constexpr int NCHUNK   = (N_NODES + 255) / 256;   // 196 scan chunks

// Workspace layout in 4-byte units. Total 11,433,472 u32 = 45.7 MB.
constexpr size_t OFF_DEG  = 0;                                  // f32 [50000]
constexpr size_t OFF_DIS  = 50000;                              // f32 [50000]
constexpr size_t OFF_POOL = 100000;                             // f32 [256*128]
constexpr size_t OFF_CNT  = OFF_POOL + (size_t)N_GRAPHS * EMB;  // f32 [256]
constexpr size_t OFF_HIST = 133120;                             // i32 [50000]
constexpr size_t OFF_RS   = OFF_HIST + N_NODES;                 // i32 [50000]
constexpr size_t OFF_BSUM = OFF_RS + N_NODES;                   // i32 [256]
constexpr size_t OFF_REC  = 233472;                             // uint2 [800000] (8B-aligned)
constexpr size_t OFF_H1   = OFF_REC + 2 * (size_t)N_EDGES;      // f32 [50000*64]
constexpr size_t OFF_H1P  = OFF_H1 + (size_t)N_NODES * HID;     // f32 [50000*64]
constexpr size_t OFF_H2P  = OFF_H1P;  // f32 [50000*128]; overlays h1p (dead after gather1)

// ---- degree (with self-loop) + histogram, fused ----
__global__ void k_deg_hist(const int* __restrict__ dst, const float* __restrict__ ew,
                           float* __restrict__ deg, int* __restrict__ hist) {
    int e = blockIdx.x * blockDim.x + threadIdx.x;
    if (e < N_EDGES) {
        int d = dst[e];
        atomicAdd(&deg[d], ew[e]);
        atomicAdd(&hist[d], 1);
    }
}

__global__ void k_dis(float* __restrict__ deg, float* __restrict__ dis) {
    int i = blockIdx.x * blockDim.x + threadIdx.x;
    if (i < N_NODES) {
        float d = deg[i] + 1.0f;        // + self-loop weight 1; always > 0
        deg[i] = d;
        dis[i] = rsqrtf(d);
    }
}

// ---- exclusive scan of hist[50000] -> rs ----
__global__ __launch_bounds__(256) void k_scan1(const int* __restrict__ hist,
                                               int* __restrict__ bsum) {
    __shared__ int tmp[256];
    int t = threadIdx.x;
    int idx = blockIdx.x * 256 + t;
    tmp[t] = (idx < N_NODES) ? hist[idx] : 0;
    __syncthreads();
    for (int off = 128; off > 0; off >>= 1) {
        if (t < off) tmp[t] += tmp[t + off];
        __syncthreads();
    }
    if (t == 0) bsum[blockIdx.x] = tmp[0];
}

__global__ __launch_bounds__(256) void k_scan2(int* __restrict__ bsum) {
    __shared__ int tmp[256];
    int t = threadIdx.x;
    int v = (t < NCHUNK) ? bsum[t] : 0;
    tmp[t] = v;
    __syncthreads();
    for (int off = 1; off < 256; off <<= 1) {
        int add = (t >= off) ? tmp[t - off] : 0;
        __syncthreads();
        tmp[t] += add;
        __syncthreads();
    }
    // exclusive
    if (t < NCHUNK) bsum[t] = tmp[t] - v;
}

__global__ __launch_bounds__(256) void k_scan3(const int* __restrict__ hist,
                                               const int* __restrict__ bsum,
                                               int* __restrict__ rs) {
    __shared__ int tmp[256];
    int t = threadIdx.x;
    int idx = blockIdx.x * 256 + t;
    int v = (idx < N_NODES) ? hist[idx] : 0;
    tmp[t] = v;
    __syncthreads();
    for (int off = 1; off < 256; off <<= 1) {
        int add = (t >= off) ? tmp[t - off] : 0;
        __syncthreads();
        tmp[t] += add;
        __syncthreads();
    }
    if (idx < N_NODES) rs[idx] = bsum[blockIdx.x] + tmp[t] - v;   // exclusive start
}

// ---- CSR build: rec[pos] = (src, norm); rs[d] advances to end(d) ----
__global__ void k_build(const int* __restrict__ src, const int* __restrict__ dst,
                        const float* __restrict__ ew, const float* __restrict__ dis,
                        int* __restrict__ rs, uint2* __restrict__ rec) {
    int e = blockIdx.x * blockDim.x + threadIdx.x;
    if (e >= N_EDGES) return;
    int s = src[e], d = dst[e];
    float norm = dis[s] * ew[e] * dis[d];
    int pos = atomicAdd(&rs[d], 1);
    rec[pos] = make_uint2((unsigned)s, __float_as_uint(norm));
}

// ---- h1_pre = x @ W1 : [N,128]x[128,64]. 256 thr = 4 nodes x 64 cols ----
__global__ __launch_bounds__(256) void k_gemm1(const float* __restrict__ x,
                                               const float* __restrict__ W1,
                                               float* __restrict__ h) {
    __shared__ float Ws[IN_DIM * HID];
    __shared__ float xs[4][IN_DIM];
    int tid = threadIdx.x;
    for (int i = tid; i < IN_DIM * HID; i += 256) Ws[i] = W1[i];
    int base = blockIdx.x * 4;
    for (int i = tid; i < 4 * IN_DIM; i += 256) {
        int ln = i >> 7, k = i & 127;
        int node = base + ln;
        xs[ln][k] = (node < N_NODES) ? x[(size_t)node * IN_DIM + k] : 0.f;
    }
    __syncthreads();
    int ln = tid >> 6, j = tid & 63;
    int node = base + ln;
    float acc = 0.f;
    #pragma unroll 8
    for (int k = 0; k < IN_DIM; ++k) acc += xs[ln][k] * Ws[k * HID + j];
    if (node < N_NODES) h[(size_t)node * HID + j] = acc;
}

// ---- gather1: one wave per node; h1 = relu(sum_e h1p[src]*norm + h1p[n]/deg + b1) ----
__global__ __launch_bounds__(256) void k_gather1(const uint2* __restrict__ rec,
                                                 const int* __restrict__ rs,
                                                 const float* __restrict__ dis,
                                                 const float* __restrict__ h1p,
                                                 const float* __restrict__ b1,
                                                 float* __restrict__ h1) {
    int wave = (blockIdx.x * 256 + threadIdx.x) >> 6;
    int lane = threadIdx.x & 63;
    if (wave >= N_NODES) return;
    int n = wave;
    int begin = (n == 0) ? 0 : rs[n - 1];   // post-build: rs[k] = end(k)
    int end = rs[n];
    float acc = 0.f;
    for (int k = begin; k < end; ++k) {
        uint2 r = rec[k];
        float norm = __uint_as_float(r.y);
        acc += h1p[(size_t)r.x * HID + lane] * norm;
    }
    float di = dis[n];
    acc += h1p[(size_t)n * HID + lane] * (di * di);   // self-loop: 1/deg
    float v = acc + b1[lane];
    h1[(size_t)n * HID + lane] = v > 0.f ? v : 0.f;
}

// ---- h2_pre = h1 @ W2 : [N,64]x[64,128]. 256 thr = 2 nodes x 128 cols ----
__global__ __launch_bounds__(256) void k_gemm2(const float* __restrict__ h1,
                                               const float* __restrict__ W2,
                                               float* __restrict__ h) {
    __shared__ float Ws[HID * EMB];
    __shared__ float xs[2][HID];
    int tid = threadIdx.x;
    for (int i = tid; i < HID * EMB; i += 256) Ws[i] = W2[i];
    int base = blockIdx.x * 2;
    for (int i = tid; i < 2 * HID; i += 256) {
        int ln = i >> 6, k = i & 63;
        int node = base + ln;
        xs[ln][k] = (node < N_NODES) ? h1[(size_t)node * HID + k] : 0.f;
    }
    __syncthreads();
    int ln = tid >> 7, j = tid & 127;
    int node = base + ln;
    float acc = 0.f;
    #pragma unroll 8
    for (int k = 0; k < HID; ++k) acc += xs[ln][k] * Ws[k * EMB + j];
    if (node < N_NODES) h[(size_t)node * EMB + j] = acc;
}

// ---- gather2: one wave per node (float2/lane); fused relu + mean-pool accumulate ----
__global__ __launch_bounds__(256) void k_gather2(const uint2* __restrict__ rec,
                                                 const int* __restrict__ rs,
                                                 const float* __restrict__ dis,
                                                 const float* __restrict__ h2p,
                                                 const float* __restrict__ b2,
                                                 const int* __restrict__ batch,
                                                 float* __restrict__ pool,
                                                 float* __restrict__ cnt) {
    int wave = (blockIdx.x * 256 + threadIdx.x) >> 6;
    int lane = threadIdx.x & 63;
    if (wave >= N_NODES) return;
    int n = wave;
    int begin = (n == 0) ? 0 : rs[n - 1];
    int end = rs[n];
    const float2* H = (const float2*)h2p;
    float2 acc = make_float2(0.f, 0.f);
    for (int k = begin; k < end; ++k) {
        uint2 r = rec[k];
        float norm = __uint_as_float(r.y);
        float2 hv = H[(size_t)r.x * 64 + lane];
        acc.x += hv.x * norm;
        acc.y += hv.y * norm;
    }
    float di = dis[n];
    float2 hs = H[(size_t)n * 64 + lane];
    acc.x += hs.x * (di * di);
    acc.y += hs.y * (di * di);
    float vx = acc.x + b2[2 * lane];
    float vy = acc.y + b2[2 * lane + 1];
    vx = vx > 0.f ? vx : 0.f;
    vy = vy > 0.f ? vy : 0.f;
    int g = batch[n];
    atomicAdd(&pool[(size_t)g * EMB + 2 * lane], vx);
    atomicAdd(&pool[(size_t)g * EMB + 2 * lane + 1], vy);
    if (lane == 0) atomicAdd(&cnt[g], 1.0f);
}

__global__ void k_divide(const float* __restrict__ pool, const float* __restrict__ cnt,
                         float* __restrict__ out) {
    int idx = blockIdx.x * blockDim.x + threadIdx.x;
    if (idx >= N_GRAPHS * EMB) return;
    float c = cnt[idx >> 7];
    out[idx] = pool[idx] / fmaxf(c, 1.0f);
}

extern "C" void kernel_launch(void* const* d_in, const int* in_sizes, int n_in,
                              void* d_out, int out_size, void* d_ws, size_t ws_size,
                              hipStream_t stream) {
    const float* x     = (const float*)d_in[0];
    const int*   eidx  = (const int*)d_in[1];     // [2, E]: src then dst
    const float* ew    = (const float*)d_in[2];
    const int*   batch = (const int*)d_in[3];
    const float* W1    = (const float*)d_in[4];
    const float* b1    = (const float*)d_in[5];
    const float* W2    = (const float*)d_in[6];
    const float* b2    = (const float*)d_in[7];
    float* out = (float*)d_out;

    const int* src = eidx;
    const int* dst = eidx + N_EDGES;

    float* ws   = (float*)d_ws;
    float* deg  = ws + OFF_DEG;
    float* dis  = ws + OFF_DIS;
    float* pool = ws + OFF_POOL;
    float* cnt  = ws + OFF_CNT;
    int*   hist = (int*)(ws + OFF_HIST);
    int*   rs   = (int*)(ws + OFF_RS);
    int*   bsum = (int*)(ws + OFF_BSUM);
    uint2* rec  = (uint2*)(ws + OFF_REC);
    float* h1   = ws + OFF_H1;
    float* h1p  = ws + OFF_H1P;
    float* h2p  = ws + OFF_H2P;   // overlays h1p (dead after gather1)

    // Zero the header region (deg, dis, pool, cnt, hist) in one shot.
    hipMemsetAsync(ws, 0, OFF_REC * sizeof(float), stream);

    // Degree + histogram + normalization.
    k_deg_hist<<<(N_EDGES + 255) / 256, 256, 0, stream>>>(dst, ew, deg, hist);
    k_dis<<<(N_NODES + 255) / 256, 256, 0, stream>>>(deg, dis);

    // Exclusive scan of hist -> rs.
    k_scan1<<<NCHUNK, 256, 0, stream>>>(hist, bsum);
    k_scan2<<<1, 256, 0, stream>>>(bsum);
    k_scan3<<<NCHUNK, 256, 0, stream>>>(hist, bsum, rs);

    // Layer-1 linear (independent of CSR build).
    k_gemm1<<<(N_NODES + 3) / 4, 256, 0, stream>>>(x, W1, h1p);

    // CSR build (rs[d] advances to end(d)).
    k_build<<<(N_EDGES + 255) / 256, 256, 0, stream>>>(src, dst, ew, dis, rs, rec);

    // Layer 1 aggregate (gather, no atomics) + bias + relu.
    k_gather1<<<(N_NODES + 3) / 4, 256, 0, stream>>>(rec, rs, dis, h1p, b1, h1);

    // Layer-2 linear (h2p overlays dead h1p).
    k_gemm2<<<(N_NODES + 1) / 2, 256, 0, stream>>>(h1, W2, h2p);

    // Layer 2 aggregate + relu + fused mean-pool accumulation.
    k_gather2<<<(N_NODES + 3) / 4, 256, 0, stream>>>(rec, rs, dis, h2p, b2, batch, pool, cnt);

    k_divide<<<(N_GRAPHS * EMB + 255) / 256, 256, 0, stream>>>(pool, cnt, out);
}

// Round 3
// 540.393 us; speedup vs baseline: 1.8188x; 1.1700x over previous
//
#include <hip/hip_runtime.h>

// GCNEncoder round 3: CSR gather-form + algebraic reorder of layer 2
// (Agg(h1@W2) == (Agg h1)@W2) so BOTH gathers run in the 64-dim space,
// dual-edge-per-wave gather for 2x MLP, GEMM2+ReLU+pool fused.
constexpr int N_NODES  = 50000;
constexpr int N_EDGES  = 800000;
constexpr int N_GRAPHS = 256;
constexpr int IN_DIM   = 128;
constexpr int HID      = 64;
constexpr int EMB      = 128;
constexpr int NCHUNK   = (N_NODES + 255) / 256;   // 196 scan chunks

// Workspace layout in 4-byte units (33 MB total; ws held 45.7 MB in round 2).
constexpr size_t OFF_DEG  = 0;                                  // f32 [50000]
constexpr size_t OFF_DIS  = 50000;                              // f32 [50000]
constexpr size_t OFF_POOL = 100000;                             // f32 [256*128]
constexpr size_t OFF_CNT  = OFF_POOL + (size_t)N_GRAPHS * EMB;  // f32 [256]
constexpr size_t OFF_HIST = 133120;                             // i32 [50000]
constexpr size_t OFF_RS   = OFF_HIST + N_NODES;                 // i32 [50000]
constexpr size_t OFF_BSUM = OFF_RS + N_NODES;                   // i32 [256]
constexpr size_t OFF_REC  = 233472;                             // uint2 [800000] (8B-aligned)
constexpr size_t OFF_H1   = OFF_REC + 2 * (size_t)N_EDGES;      // f32 [50000*64]
constexpr size_t OFF_H1P  = OFF_H1 + (size_t)N_NODES * HID;     // f32 [50000*64]
constexpr size_t OFF_AGG2 = OFF_H1P;   // f32 [50000*64]; overlays h1p (dead after gather1)

// ---- degree (pre-self-loop) + CSR histogram, fused ----
__global__ void k_deg_hist(const int* __restrict__ dst, const float* __restrict__ ew,
                           float* __restrict__ deg, int* __restrict__ hist) {
    int e = blockIdx.x * blockDim.x + threadIdx.x;
    if (e < N_EDGES) {
        int d = dst[e];
        atomicAdd(&deg[d], ew[e]);
        atomicAdd(&hist[d], 1);
    }
}

// dis = rsqrt(deg+1); also accumulate per-graph node counts (cnt zeroed by memset).
__global__ void k_dis(float* __restrict__ deg, float* __restrict__ dis,
                      const int* __restrict__ batch, float* __restrict__ cnt) {
    int i = blockIdx.x * blockDim.x + threadIdx.x;
    if (i < N_NODES) {
        float d = deg[i] + 1.0f;        // + self-loop weight 1; always > 0
        dis[i] = rsqrtf(d);
        atomicAdd(&cnt[batch[i]], 1.0f);
    }
}

// ---- exclusive scan of hist[50000] -> rs ----
__global__ __launch_bounds__(256) void k_scan1(const int* __restrict__ hist,
                                               int* __restrict__ bsum) {
    __shared__ int tmp[256];
    int t = threadIdx.x;
    int idx = blockIdx.x * 256 + t;
    tmp[t] = (idx < N_NODES) ? hist[idx] : 0;
    __syncthreads();
    for (int off = 128; off > 0; off >>= 1) {
        if (t < off) tmp[t] += tmp[t + off];
        __syncthreads();
    }
    if (t == 0) bsum[blockIdx.x] = tmp[0];
}

__global__ __launch_bounds__(256) void k_scan2(int* __restrict__ bsum) {
    __shared__ int tmp[256];
    int t = threadIdx.x;
    int v = (t < NCHUNK) ? bsum[t] : 0;
    tmp[t] = v;
    __syncthreads();
    for (int off = 1; off < 256; off <<= 1) {
        int add = (t >= off) ? tmp[t - off] : 0;
        __syncthreads();
        tmp[t] += add;
        __syncthreads();
    }
    if (t < NCHUNK) bsum[t] = tmp[t] - v;   // exclusive
}

__global__ __launch_bounds__(256) void k_scan3(const int* __restrict__ hist,
                                               const int* __restrict__ bsum,
                                               int* __restrict__ rs) {
    __shared__ int tmp[256];
    int t = threadIdx.x;
    int idx = blockIdx.x * 256 + t;
    int v = (idx < N_NODES) ? hist[idx] : 0;
    tmp[t] = v;
    __syncthreads();
    for (int off = 1; off < 256; off <<= 1) {
        int add = (t >= off) ? tmp[t - off] : 0;
        __syncthreads();
        tmp[t] += add;
        __syncthreads();
    }
    if (idx < N_NODES) rs[idx] = bsum[blockIdx.x] + tmp[t] - v;   // exclusive start
}

// ---- CSR build: rec[pos] = (src, norm); rs[d] advances to end(d) ----
__global__ void k_build(const int* __restrict__ src, const int* __restrict__ dst,
                        const float* __restrict__ ew, const float* __restrict__ dis,
                        int* __restrict__ rs, uint2* __restrict__ rec) {
    int e = blockIdx.x * blockDim.x + threadIdx.x;
    if (e >= N_EDGES) return;
    int s = src[e], d = dst[e];
    float norm = dis[s] * ew[e] * dis[d];
    int pos = atomicAdd(&rs[d], 1);
    rec[pos] = make_uint2((unsigned)s, __float_as_uint(norm));
}

// ---- h1_pre = x @ W1 : [N,128]x[128,64]. 16 nodes/block, 16 thr x float4 per node ----
__global__ __launch_bounds__(256) void k_gemm1(const float* __restrict__ x,
                                               const float* __restrict__ W1,
                                               float* __restrict__ h) {
    __shared__ float Ws[IN_DIM * HID];      // 32 KB
    __shared__ float xs[16][IN_DIM + 1];    // pad -> bank-spread for xs[ln][k]
    int tid = threadIdx.x;
    const float4* W4 = (const float4*)W1;
    float4* Ws4 = (float4*)Ws;
    for (int i = tid; i < IN_DIM * HID / 4; i += 256) Ws4[i] = W4[i];
    int base = blockIdx.x * 16;
    for (int i = tid; i < 16 * IN_DIM; i += 256) {
        int ln = i >> 7, k = i & 127;
        xs[ln][k] = x[(size_t)(base + ln) * IN_DIM + k];
    }
    __syncthreads();
    int ln = tid >> 4;            // node in block
    int jc = (tid & 15) * 4;      // column base
    float4 acc = make_float4(0.f, 0.f, 0.f, 0.f);
    #pragma unroll 4
    for (int k = 0; k < IN_DIM; ++k) {
        float a = xs[ln][k];
        float4 w = *(const float4*)&Ws[k * HID + jc];
        acc.x += a * w.x; acc.y += a * w.y; acc.z += a * w.z; acc.w += a * w.w;
    }
    *(float4*)&h[(size_t)(base + ln) * HID + jc] = acc;
}

// ---- 64-dim CSR gather: out[n] = sum_e norm*T[src] + dis^2*T[n] (+bias,relu) ----
// One wave per node. Lanes 0-31 fetch even-offset records, lanes 32-63 odd:
// one load instruction gathers TWO 256B rows; unroll x2 -> 4 rows in flight.
template <bool RELU_BIAS>
__global__ __launch_bounds__(256) void k_gather64(const uint2* __restrict__ rec,
                                                  const int* __restrict__ rs,
                                                  const float* __restrict__ dis,
                                                  const float* __restrict__ T,
                                                  const float* __restrict__ bias,
                                                  float* __restrict__ out) {
    int wave = (blockIdx.x * 256 + threadIdx.x) >> 6;
    int lane = threadIdx.x & 63;
    int half = lane >> 5;
    int l    = lane & 31;         // float2 index within row
    if (wave >= N_NODES) return;
    int n = wave;
    int begin = (n == 0) ? 0 : rs[n - 1];   // post-build: rs[k] = end(k)
    int end = rs[n];
    const float2* T2 = (const float2*)T;

    float ax0 = 0.f, ay0 = 0.f, ax1 = 0.f, ay1 = 0.f;
    int k = begin + half;
    while (k + 2 < end) {                   // 2 records per half per iter
        uint2 r0 = rec[k];
        uint2 r1 = rec[k + 2];
        float2 t0 = T2[(size_t)r0.x * 32 + l];
        float2 t1 = T2[(size_t)r1.x * 32 + l];
        float n0 = __uint_as_float(r0.y);
        float n1 = __uint_as_float(r1.y);
        ax0 += t0.x * n0; ay0 += t0.y * n0;
        ax1 += t1.x * n1; ay1 += t1.y * n1;
        k += 4;
    }
    if (k < end) {
        uint2 r = rec[k];
        float2 t = T2[(size_t)r.x * 32 + l];
        float nn = __uint_as_float(r.y);
        ax0 += t.x * nn; ay0 += t.y * nn;
    }
    float ax = ax0 + ax1, ay = ay0 + ay1;
    if (half == 0) {                        // self-loop term, counted once
        float di = dis[n];
        float2 t = T2[(size_t)n * 32 + l];
        ax += t.x * di * di; ay += t.y * di * di;
    }
    ax += __shfl_xor(ax, 32, 64);           // combine halves
    ay += __shfl_xor(ay, 32, 64);
    if (half == 0) {
        if (RELU_BIAS) {
            const float2* B2 = (const float2*)bias;
            float2 b = B2[l];
            ax += b.x; ay += b.y;
            ax = ax > 0.f ? ax : 0.f;
            ay = ay > 0.f ? ay : 0.f;
        }
        ((float2*)out)[(size_t)n * 32 + l] = make_float2(ax, ay);
    }
}

// ---- fused: h2 = relu(agg2 @ W2 + b2); pool[batch] += h2. 8 nodes/block ----
__global__ __launch_bounds__(256) void k_gemm2_pool(const float* __restrict__ agg,
                                                    const float* __restrict__ W2,
                                                    const float* __restrict__ b2,
                                                    const int* __restrict__ batch,
                                                    float* __restrict__ pool) {
    __shared__ float Ws[HID * EMB];         // 32 KB
    __shared__ float as[8][HID + 1];        // pad -> bank-spread
    int tid = threadIdx.x;
    const float4* W4 = (const float4*)W2;
    float4* Ws4 = (float4*)Ws;
    for (int i = tid; i < HID * EMB / 4; i += 256) Ws4[i] = W4[i];
    int base = blockIdx.x * 8;
    for (int i = tid; i < 8 * HID; i += 256) {
        int ln = i >> 6, k = i & 63;
        as[ln][k] = agg[(size_t)(base + ln) * HID + k];
    }
    __syncthreads();
    int ln = tid >> 5;            // node in block
    int jc = (tid & 31) * 4;      // column base
    float4 acc = make_float4(b2[jc], b2[jc + 1], b2[jc + 2], b2[jc + 3]);
    #pragma unroll 4
    for (int k = 0; k < HID; ++k) {
        float a = as[ln][k];
        float4 w = *(const float4*)&Ws[k * EMB + jc];
        acc.x += a * w.x; acc.y += a * w.y; acc.z += a * w.z; acc.w += a * w.w;
    }
    acc.x = acc.x > 0.f ? acc.x : 0.f;
    acc.y = acc.y > 0.f ? acc.y : 0.f;
    acc.z = acc.z > 0.f ? acc.z : 0.f;
    acc.w = acc.w > 0.f ? acc.w : 0.f;
    int g = batch[base + ln];
    float* p = &pool[(size_t)g * EMB + jc];
    atomicAdd(p + 0, acc.x);
    atomicAdd(p + 1, acc.y);
    atomicAdd(p + 2, acc.z);
    atomicAdd(p + 3, acc.w);
}

__global__ void k_divide(const float* __restrict__ pool, const float* __restrict__ cnt,
                         float* __restrict__ out) {
    int idx = blockIdx.x * blockDim.x + threadIdx.x;
    if (idx >= N_GRAPHS * EMB) return;
    float c = cnt[idx >> 7];
    out[idx] = pool[idx] / fmaxf(c, 1.0f);
}

extern "C" void kernel_launch(void* const* d_in, const int* in_sizes, int n_in,
                              void* d_out, int out_size, void* d_ws, size_t ws_size,
                              hipStream_t stream) {
    const float* x     = (const float*)d_in[0];
    const int*   eidx  = (const int*)d_in[1];     // [2, E]: src then dst
    const float* ew    = (const float*)d_in[2];
    const int*   batch = (const int*)d_in[3];
    const float* W1    = (const float*)d_in[4];
    const float* b1    = (const float*)d_in[5];
    const float* W2    = (const float*)d_in[6];
    const float* b2    = (const float*)d_in[7];
    float* out = (float*)d_out;

    const int* src = eidx;
    const int* dst = eidx + N_EDGES;

    float* ws   = (float*)d_ws;
    float* deg  = ws + OFF_DEG;
    float* dis  = ws + OFF_DIS;
    float* pool = ws + OFF_POOL;
    float* cnt  = ws + OFF_CNT;
    int*   hist = (int*)(ws + OFF_HIST);
    int*   rs   = (int*)(ws + OFF_RS);
    int*   bsum = (int*)(ws + OFF_BSUM);
    uint2* rec  = (uint2*)(ws + OFF_REC);
    float* h1   = ws + OFF_H1;
    float* h1p  = ws + OFF_H1P;
    float* agg2 = ws + OFF_AGG2;   // overlays h1p (dead after gather1)

    // Zero header region (deg, dis, pool, cnt, hist, rs, bsum) in one shot.
    hipMemsetAsync(ws, 0, OFF_REC * sizeof(float), stream);

    // Degree + histogram + normalization (+ per-graph counts).
    k_deg_hist<<<(N_EDGES + 255) / 256, 256, 0, stream>>>(dst, ew, deg, hist);
    k_dis<<<(N_NODES + 255) / 256, 256, 0, stream>>>(deg, dis, batch, cnt);

    // Exclusive scan of hist -> rs.
    k_scan1<<<NCHUNK, 256, 0, stream>>>(hist, bsum);
    k_scan2<<<1, 256, 0, stream>>>(bsum);
    k_scan3<<<NCHUNK, 256, 0, stream>>>(hist, bsum, rs);

    // Layer-1 linear (independent of CSR build).
    k_gemm1<<<N_NODES / 16, 256, 0, stream>>>(x, W1, h1p);

    // CSR build (rs[d] advances to end(d)).
    k_build<<<(N_EDGES + 255) / 256, 256, 0, stream>>>(src, dst, ew, dis, rs, rec);

    // Layer 1 aggregate + bias + relu (64-dim gather).
    k_gather64<true><<<N_NODES / 4, 256, 0, stream>>>(rec, rs, dis, h1p, b1, h1);

    // Layer 2 aggregate BEFORE the linear (Agg(h1@W2) == (Agg h1)@W2).
    k_gather64<false><<<N_NODES / 4, 256, 0, stream>>>(rec, rs, dis, h1, nullptr, agg2);

    // Fused layer-2 linear + relu + mean-pool accumulate.
    k_gemm2_pool<<<N_NODES / 8, 256, 0, stream>>>(agg2, W2, b2, batch, pool);

    k_divide<<<(N_GRAPHS * EMB + 255) / 256, 256, 0, stream>>>(pool, cnt, out);
}

// Round 4
// 424.723 us; speedup vs baseline: 2.3141x; 1.2723x over previous
//
#include <hip/hip_runtime.h>

// GCNEncoder round 4: round-3 structure + atomic-contention fix in gemm2_pool.
// batch_vec is SORTED -> run-length accumulate pooled sums in registers and
// flush one atomic per (graph-run, thread) instead of one per node.
constexpr int N_NODES  = 50000;
constexpr int N_EDGES  = 800000;
constexpr int N_GRAPHS = 256;
constexpr int IN_DIM   = 128;
constexpr int HID      = 64;
constexpr int EMB      = 128;
constexpr int NCHUNK   = (N_NODES + 255) / 256;   // 196 scan chunks
constexpr int NB2      = 64;                      // nodes per gemm2_pool block

// Workspace layout in 4-byte units (33 MB total; 45.7 MB proven available).
constexpr size_t OFF_DEG  = 0;                                  // f32 [50000]
constexpr size_t OFF_DIS  = 50000;                              // f32 [50000]
constexpr size_t OFF_POOL = 100000;                             // f32 [256*128]
constexpr size_t OFF_CNT  = OFF_POOL + (size_t)N_GRAPHS * EMB;  // f32 [256]
constexpr size_t OFF_HIST = 133120;                             // i32 [50000]
constexpr size_t OFF_RS   = OFF_HIST + N_NODES;                 // i32 [50000]
constexpr size_t OFF_BSUM = OFF_RS + N_NODES;                   // i32 [256]
constexpr size_t OFF_REC  = 233472;                             // uint2 [800000] (8B-aligned)
constexpr size_t OFF_H1   = OFF_REC + 2 * (size_t)N_EDGES;      // f32 [50000*64]
constexpr size_t OFF_H1P  = OFF_H1 + (size_t)N_NODES * HID;     // f32 [50000*64]
constexpr size_t OFF_AGG2 = OFF_H1P;   // f32 [50000*64]; overlays h1p (dead after gather1)

// ---- degree (pre-self-loop) + CSR histogram, fused ----
__global__ void k_deg_hist(const int* __restrict__ dst, const float* __restrict__ ew,
                           float* __restrict__ deg, int* __restrict__ hist) {
    int e = blockIdx.x * blockDim.x + threadIdx.x;
    if (e < N_EDGES) {
        int d = dst[e];
        atomicAdd(&deg[d], ew[e]);
        atomicAdd(&hist[d], 1);
    }
}

// dis = rsqrt(deg+1); also accumulate per-graph node counts (cnt zeroed by memset).
__global__ void k_dis(float* __restrict__ deg, float* __restrict__ dis,
                      const int* __restrict__ batch, float* __restrict__ cnt) {
    int i = blockIdx.x * blockDim.x + threadIdx.x;
    if (i < N_NODES) {
        float d = deg[i] + 1.0f;        // + self-loop weight 1; always > 0
        dis[i] = rsqrtf(d);
        atomicAdd(&cnt[batch[i]], 1.0f);
    }
}

// ---- exclusive scan of hist[50000] -> rs ----
__global__ __launch_bounds__(256) void k_scan1(const int* __restrict__ hist,
                                               int* __restrict__ bsum) {
    __shared__ int tmp[256];
    int t = threadIdx.x;
    int idx = blockIdx.x * 256 + t;
    tmp[t] = (idx < N_NODES) ? hist[idx] : 0;
    __syncthreads();
    for (int off = 128; off > 0; off >>= 1) {
        if (t < off) tmp[t] += tmp[t + off];
        __syncthreads();
    }
    if (t == 0) bsum[blockIdx.x] = tmp[0];
}

__global__ __launch_bounds__(256) void k_scan2(int* __restrict__ bsum) {
    __shared__ int tmp[256];
    int t = threadIdx.x;
    int v = (t < NCHUNK) ? bsum[t] : 0;
    tmp[t] = v;
    __syncthreads();
    for (int off = 1; off < 256; off <<= 1) {
        int add = (t >= off) ? tmp[t - off] : 0;
        __syncthreads();
        tmp[t] += add;
        __syncthreads();
    }
    if (t < NCHUNK) bsum[t] = tmp[t] - v;   // exclusive
}

__global__ __launch_bounds__(256) void k_scan3(const int* __restrict__ hist,
                                               const int* __restrict__ bsum,
                                               int* __restrict__ rs) {
    __shared__ int tmp[256];
    int t = threadIdx.x;
    int idx = blockIdx.x * 256 + t;
    int v = (idx < N_NODES) ? hist[idx] : 0;
    tmp[t] = v;
    __syncthreads();
    for (int off = 1; off < 256; off <<= 1) {
        int add = (t >= off) ? tmp[t - off] : 0;
        __syncthreads();
        tmp[t] += add;
        __syncthreads();
    }
    if (idx < N_NODES) rs[idx] = bsum[blockIdx.x] + tmp[t] - v;   // exclusive start
}

// ---- CSR build: rec[pos] = (src, norm); rs[d] advances to end(d) ----
__global__ void k_build(const int* __restrict__ src, const int* __restrict__ dst,
                        const float* __restrict__ ew, const float* __restrict__ dis,
                        int* __restrict__ rs, uint2* __restrict__ rec) {
    int e = blockIdx.x * blockDim.x + threadIdx.x;
    if (e >= N_EDGES) return;
    int s = src[e], d = dst[e];
    float norm = dis[s] * ew[e] * dis[d];
    int pos = atomicAdd(&rs[d], 1);
    rec[pos] = make_uint2((unsigned)s, __float_as_uint(norm));
}

// ---- h1_pre = x @ W1 : [N,128]x[128,64]. 16 nodes/block, 16 thr x float4 per node ----
__global__ __launch_bounds__(256) void k_gemm1(const float* __restrict__ x,
                                               const float* __restrict__ W1,
                                               float* __restrict__ h) {
    __shared__ float Ws[IN_DIM * HID];      // 32 KB
    __shared__ float xs[16][IN_DIM + 1];    // pad -> bank-spread for xs[ln][k]
    int tid = threadIdx.x;
    const float4* W4 = (const float4*)W1;
    float4* Ws4 = (float4*)Ws;
    for (int i = tid; i < IN_DIM * HID / 4; i += 256) Ws4[i] = W4[i];
    int base = blockIdx.x * 16;
    for (int i = tid; i < 16 * IN_DIM; i += 256) {
        int ln = i >> 7, k = i & 127;
        xs[ln][k] = x[(size_t)(base + ln) * IN_DIM + k];
    }
    __syncthreads();
    int ln = tid >> 4;            // node in block
    int jc = (tid & 15) * 4;      // column base
    float4 acc = make_float4(0.f, 0.f, 0.f, 0.f);
    #pragma unroll 4
    for (int k = 0; k < IN_DIM; ++k) {
        float a = xs[ln][k];
        float4 w = *(const float4*)&Ws[k * HID + jc];
        acc.x += a * w.x; acc.y += a * w.y; acc.z += a * w.z; acc.w += a * w.w;
    }
    *(float4*)&h[(size_t)(base + ln) * HID + jc] = acc;
}

// ---- 64-dim CSR gather: out[n] = sum_e norm*T[src] + dis^2*T[n] (+bias,relu) ----
// One wave per node. Lanes 0-31 fetch even-offset records, lanes 32-63 odd:
// one load instruction gathers TWO 256B rows; unroll x2 -> 4 rows in flight.
template <bool RELU_BIAS>
__global__ __launch_bounds__(256) void k_gather64(const uint2* __restrict__ rec,
                                                  const int* __restrict__ rs,
                                                  const float* __restrict__ dis,
                                                  const float* __restrict__ T,
                                                  const float* __restrict__ bias,
                                                  float* __restrict__ out) {
    int wave = (blockIdx.x * 256 + threadIdx.x) >> 6;
    int lane = threadIdx.x & 63;
    int half = lane >> 5;
    int l    = lane & 31;         // float2 index within row
    if (wave >= N_NODES) return;
    int n = wave;
    int begin = (n == 0) ? 0 : rs[n - 1];   // post-build: rs[k] = end(k)
    int end = rs[n];
    const float2* T2 = (const float2*)T;

    float ax0 = 0.f, ay0 = 0.f, ax1 = 0.f, ay1 = 0.f;
    int k = begin + half;
    while (k + 2 < end) {                   // 2 records per half per iter
        uint2 r0 = rec[k];
        uint2 r1 = rec[k + 2];
        float2 t0 = T2[(size_t)r0.x * 32 + l];
        float2 t1 = T2[(size_t)r1.x * 32 + l];
        float n0 = __uint_as_float(r0.y);
        float n1 = __uint_as_float(r1.y);
        ax0 += t0.x * n0; ay0 += t0.y * n0;
        ax1 += t1.x * n1; ay1 += t1.y * n1;
        k += 4;
    }
    if (k < end) {
        uint2 r = rec[k];
        float2 t = T2[(size_t)r.x * 32 + l];
        float nn = __uint_as_float(r.y);
        ax0 += t.x * nn; ay0 += t.y * nn;
    }
    float ax = ax0 + ax1, ay = ay0 + ay1;
    if (half == 0) {                        // self-loop term, counted once
        float di = dis[n];
        float2 t = T2[(size_t)n * 32 + l];
        ax += t.x * di * di; ay += t.y * di * di;
    }
    ax += __shfl_xor(ax, 32, 64);           // combine halves
    ay += __shfl_xor(ay, 32, 64);
    if (half == 0) {
        if (RELU_BIAS) {
            const float2* B2 = (const float2*)bias;
            float2 b = B2[l];
            ax += b.x; ay += b.y;
            ax = ax > 0.f ? ax : 0.f;
            ay = ay > 0.f ? ay : 0.f;
        }
        ((float2*)out)[(size_t)n * 32 + l] = make_float2(ax, ay);
    }
}

// ---- fused: h2 = relu(agg2 @ W2 + b2); pool[batch] += h2 ----
// 64 contiguous nodes/block; thread (slice,colquad) walks 8 contiguous nodes,
// run-length accumulating the pooled sum in registers (batch is sorted),
// flushing atomics only on graph-id change: ~0.85M atomics vs 6.4M.
__global__ __launch_bounds__(256) void k_gemm2_pool(const float* __restrict__ agg,
                                                    const float* __restrict__ W2,
                                                    const float* __restrict__ b2,
                                                    const int* __restrict__ batch,
                                                    float* __restrict__ pool) {
    __shared__ float Ws[HID * EMB];         // 32 KB
    __shared__ float as[NB2][HID];          // 16 KB (broadcast reads -> no conflict)
    __shared__ int   bs[NB2];
    int tid = threadIdx.x;
    const float4* W4 = (const float4*)W2;
    float4* Ws4 = (float4*)Ws;
    for (int i = tid; i < HID * EMB / 4; i += 256) Ws4[i] = W4[i];
    int base = blockIdx.x * NB2;
    const float4* A4 = (const float4*)agg;
    float4* as4 = (float4*)as;
    for (int i = tid; i < NB2 * HID / 4; i += 256) {       // 1024 float4, coalesced
        int node = base + (i >> 4);
        as4[i] = (node < N_NODES) ? A4[(size_t)node * 16 + (i & 15)]
                                  : make_float4(0.f, 0.f, 0.f, 0.f);
    }
    if (tid < NB2) {
        int node = base + tid;
        bs[tid] = (node < N_NODES) ? batch[node] : -1;
    }
    __syncthreads();

    int c = tid & 31;             // column-quad id (4 cols)
    int s = tid >> 5;             // node slice 0..7 (8 contiguous nodes each)
    int jc = c * 4;
    float4 bq = *(const float4*)&b2[jc];
    float4 racc = make_float4(0.f, 0.f, 0.f, 0.f);
    int gcur = -1;
    for (int ni = s * 8; ni < s * 8 + 8; ++ni) {
        int g = bs[ni];
        if (g != gcur) {
            if (gcur >= 0) {
                float* p = &pool[(size_t)gcur * EMB + jc];
                atomicAdd(p + 0, racc.x); atomicAdd(p + 1, racc.y);
                atomicAdd(p + 2, racc.z); atomicAdd(p + 3, racc.w);
            }
            racc = make_float4(0.f, 0.f, 0.f, 0.f);
            gcur = g;
        }
        if (g < 0) continue;
        float4 acc = bq;
        #pragma unroll 8
        for (int k = 0; k < HID; ++k) {
            float a = as[ni][k];               // wave-broadcast (2 addrs/wave: free)
            float4 w = Ws4[k * 32 + c];
            acc.x += a * w.x; acc.y += a * w.y; acc.z += a * w.z; acc.w += a * w.w;
        }
        racc.x += fmaxf(acc.x, 0.f);
        racc.y += fmaxf(acc.y, 0.f);
        racc.z += fmaxf(acc.z, 0.f);
        racc.w += fmaxf(acc.w, 0.f);
    }
    if (gcur >= 0) {
        float* p = &pool[(size_t)gcur * EMB + jc];
        atomicAdd(p + 0, racc.x); atomicAdd(p + 1, racc.y);
        atomicAdd(p + 2, racc.z); atomicAdd(p + 3, racc.w);
    }
}

__global__ void k_divide(const float* __restrict__ pool, const float* __restrict__ cnt,
                         float* __restrict__ out) {
    int idx = blockIdx.x * blockDim.x + threadIdx.x;
    if (idx >= N_GRAPHS * EMB) return;
    float c = cnt[idx >> 7];
    out[idx] = pool[idx] / fmaxf(c, 1.0f);
}

extern "C" void kernel_launch(void* const* d_in, const int* in_sizes, int n_in,
                              void* d_out, int out_size, void* d_ws, size_t ws_size,
                              hipStream_t stream) {
    const float* x     = (const float*)d_in[0];
    const int*   eidx  = (const int*)d_in[1];     // [2, E]: src then dst
    const float* ew    = (const float*)d_in[2];
    const int*   batch = (const int*)d_in[3];
    const float* W1    = (const float*)d_in[4];
    const float* b1    = (const float*)d_in[5];
    const float* W2    = (const float*)d_in[6];
    const float* b2    = (const float*)d_in[7];
    float* out = (float*)d_out;

    const int* src = eidx;
    const int* dst = eidx + N_EDGES;

    float* ws   = (float*)d_ws;
    float* deg  = ws + OFF_DEG;
    float* dis  = ws + OFF_DIS;
    float* pool = ws + OFF_POOL;
    float* cnt  = ws + OFF_CNT;
    int*   hist = (int*)(ws + OFF_HIST);
    int*   rs   = (int*)(ws + OFF_RS);
    int*   bsum = (int*)(ws + OFF_BSUM);
    uint2* rec  = (uint2*)(ws + OFF_REC);
    float* h1   = ws + OFF_H1;
    float* h1p  = ws + OFF_H1P;
    float* agg2 = ws + OFF_AGG2;   // overlays h1p (dead after gather1)

    // Zero header region (deg, dis, pool, cnt, hist, rs, bsum) in one shot.
    hipMemsetAsync(ws, 0, OFF_REC * sizeof(float), stream);

    // Degree + histogram + normalization (+ per-graph counts).
    k_deg_hist<<<(N_EDGES + 255) / 256, 256, 0, stream>>>(dst, ew, deg, hist);
    k_dis<<<(N_NODES + 255) / 256, 256, 0, stream>>>(deg, dis, batch, cnt);

    // Exclusive scan of hist -> rs.
    k_scan1<<<NCHUNK, 256, 0, stream>>>(hist, bsum);
    k_scan2<<<1, 256, 0, stream>>>(bsum);
    k_scan3<<<NCHUNK, 256, 0, stream>>>(hist, bsum, rs);

    // Layer-1 linear (independent of CSR build).
    k_gemm1<<<N_NODES / 16, 256, 0, stream>>>(x, W1, h1p);

    // CSR build (rs[d] advances to end(d)).
    k_build<<<(N_EDGES + 255) / 256, 256, 0, stream>>>(src, dst, ew, dis, rs, rec);

    // Layer 1 aggregate + bias + relu (64-dim gather).
    k_gather64<true><<<N_NODES / 4, 256, 0, stream>>>(rec, rs, dis, h1p, b1, h1);

    // Layer 2 aggregate BEFORE the linear (Agg(h1@W2) == (Agg h1)@W2).
    k_gather64<false><<<N_NODES / 4, 256, 0, stream>>>(rec, rs, dis, h1, nullptr, agg2);

    // Fused layer-2 linear + relu + run-length pooled accumulate.
    k_gemm2_pool<<<(N_NODES + NB2 - 1) / NB2, 256, 0, stream>>>(agg2, W2, b2, batch, pool);

    k_divide<<<(N_GRAPHS * EMB + 255) / 256, 256, 0, stream>>>(pool, cnt, out);
}

// Round 5
// 347.485 us; speedup vs baseline: 2.8285x; 1.2223x over previous
//
#include <hip/hip_runtime.h>

// GCNEncoder round 5: round-4 structure, minus ALL same-address f32 atomic
// hotspots. Graph sizes come from sorted-batch boundary detection (k_gstart),
// not atomics. Gather unrolled to 8 row-loads in flight per wave.
constexpr int N_NODES  = 50000;
constexpr int N_EDGES  = 800000;
constexpr int N_GRAPHS = 256;
constexpr int IN_DIM   = 128;
constexpr int HID      = 64;
constexpr int EMB      = 128;
constexpr int NCHUNK   = (N_NODES + 255) / 256;   // 196 scan chunks
constexpr int NB2      = 64;                      // nodes per gemm2_pool block

// Workspace layout in 4-byte units (33 MB total; 45.7 MB proven available).
constexpr size_t OFF_DEG  = 0;                                  // f32 [50000]
constexpr size_t OFF_DIS  = 50000;                              // f32 [50000]
constexpr size_t OFF_POOL = 100000;                             // f32 [256*128]
constexpr size_t OFF_GST  = OFF_POOL + (size_t)N_GRAPHS * EMB;  // i32 [257]
constexpr size_t OFF_HIST = 133120;                             // i32 [50000]
constexpr size_t OFF_RS   = OFF_HIST + N_NODES;                 // i32 [50000]
constexpr size_t OFF_BSUM = OFF_RS + N_NODES;                   // i32 [256]
constexpr size_t OFF_REC  = 233472;                             // uint2 [800000] (8B-aligned)
constexpr size_t OFF_H1   = OFF_REC + 2 * (size_t)N_EDGES;      // f32 [50000*64]
constexpr size_t OFF_H1P  = OFF_H1 + (size_t)N_NODES * HID;     // f32 [50000*64]
constexpr size_t OFF_AGG2 = OFF_H1P;   // f32 [50000*64]; overlays h1p (dead after gather1)

// ---- degree (pre-self-loop) + CSR histogram, fused ----
__global__ void k_deg_hist(const int* __restrict__ dst, const float* __restrict__ ew,
                           float* __restrict__ deg, int* __restrict__ hist) {
    int e = blockIdx.x * blockDim.x + threadIdx.x;
    if (e < N_EDGES) {
        int d = dst[e];
        atomicAdd(&deg[d], ew[e]);
        atomicAdd(&hist[d], 1);
    }
}

// dis = rsqrt(deg+1). Pure elementwise (atomics removed -> was 78us hotspot).
__global__ void k_dis(const float* __restrict__ deg, float* __restrict__ dis) {
    int i = blockIdx.x * blockDim.x + threadIdx.x;
    if (i < N_NODES) dis[i] = rsqrtf(deg[i] + 1.0f);   // + self-loop weight 1
}

// Sorted batch -> graph start offsets via boundary detection (no atomics).
// gstart[g] = first node of graph g (empty graphs get the next start);
// gstart[N_GRAPHS] = N_NODES.  cnt[g] = gstart[g+1]-gstart[g].
__global__ void k_gstart(const int* __restrict__ batch, int* __restrict__ gstart) {
    int i = blockIdx.x * blockDim.x + threadIdx.x;
    if (i >= N_NODES) return;
    int g = batch[i];
    if (i == 0) {
        for (int gg = 0; gg <= g; ++gg) gstart[gg] = 0;
    } else {
        int gp = batch[i - 1];
        for (int gg = gp + 1; gg <= g; ++gg) gstart[gg] = i;
    }
    if (i == N_NODES - 1) {
        for (int gg = g + 1; gg <= N_GRAPHS; ++gg) gstart[gg] = N_NODES;
    }
}

// ---- exclusive scan of hist[50000] -> rs ----
__global__ __launch_bounds__(256) void k_scan1(const int* __restrict__ hist,
                                               int* __restrict__ bsum) {
    __shared__ int tmp[256];
    int t = threadIdx.x;
    int idx = blockIdx.x * 256 + t;
    tmp[t] = (idx < N_NODES) ? hist[idx] : 0;
    __syncthreads();
    for (int off = 128; off > 0; off >>= 1) {
        if (t < off) tmp[t] += tmp[t + off];
        __syncthreads();
    }
    if (t == 0) bsum[blockIdx.x] = tmp[0];
}

__global__ __launch_bounds__(256) void k_scan2(int* __restrict__ bsum) {
    __shared__ int tmp[256];
    int t = threadIdx.x;
    int v = (t < NCHUNK) ? bsum[t] : 0;
    tmp[t] = v;
    __syncthreads();
    for (int off = 1; off < 256; off <<= 1) {
        int add = (t >= off) ? tmp[t - off] : 0;
        __syncthreads();
        tmp[t] += add;
        __syncthreads();
    }
    if (t < NCHUNK) bsum[t] = tmp[t] - v;   // exclusive
}

__global__ __launch_bounds__(256) void k_scan3(const int* __restrict__ hist,
                                               const int* __restrict__ bsum,
                                               int* __restrict__ rs) {
    __shared__ int tmp[256];
    int t = threadIdx.x;
    int idx = blockIdx.x * 256 + t;
    int v = (idx < N_NODES) ? hist[idx] : 0;
    tmp[t] = v;
    __syncthreads();
    for (int off = 1; off < 256; off <<= 1) {
        int add = (t >= off) ? tmp[t - off] : 0;
        __syncthreads();
        tmp[t] += add;
        __syncthreads();
    }
    if (idx < N_NODES) rs[idx] = bsum[blockIdx.x] + tmp[t] - v;   // exclusive start
}

// ---- CSR build: rec[pos] = (src, norm); rs[d] advances to end(d) ----
__global__ void k_build(const int* __restrict__ src, const int* __restrict__ dst,
                        const float* __restrict__ ew, const float* __restrict__ dis,
                        int* __restrict__ rs, uint2* __restrict__ rec) {
    int e = blockIdx.x * blockDim.x + threadIdx.x;
    if (e >= N_EDGES) return;
    int s = src[e], d = dst[e];
    float norm = dis[s] * ew[e] * dis[d];
    int pos = atomicAdd(&rs[d], 1);
    rec[pos] = make_uint2((unsigned)s, __float_as_uint(norm));
}

// ---- h1_pre = x @ W1 : [N,128]x[128,64]. 16 nodes/block, 16 thr x float4 per node ----
__global__ __launch_bounds__(256) void k_gemm1(const float* __restrict__ x,
                                               const float* __restrict__ W1,
                                               float* __restrict__ h) {
    __shared__ float Ws[IN_DIM * HID];      // 32 KB
    __shared__ float xs[16][IN_DIM + 1];    // pad -> bank-spread for xs[ln][k]
    int tid = threadIdx.x;
    const float4* W4 = (const float4*)W1;
    float4* Ws4 = (float4*)Ws;
    for (int i = tid; i < IN_DIM * HID / 4; i += 256) Ws4[i] = W4[i];
    int base = blockIdx.x * 16;
    for (int i = tid; i < 16 * IN_DIM; i += 256) {
        int ln = i >> 7, k = i & 127;
        xs[ln][k] = x[(size_t)(base + ln) * IN_DIM + k];
    }
    __syncthreads();
    int ln = tid >> 4;            // node in block
    int jc = (tid & 15) * 4;      // column base
    float4 acc = make_float4(0.f, 0.f, 0.f, 0.f);
    #pragma unroll 4
    for (int k = 0; k < IN_DIM; ++k) {
        float a = xs[ln][k];
        float4 w = *(const float4*)&Ws[k * HID + jc];
        acc.x += a * w.x; acc.y += a * w.y; acc.z += a * w.z; acc.w += a * w.w;
    }
    *(float4*)&h[(size_t)(base + ln) * HID + jc] = acc;
}

// ---- 64-dim CSR gather: out[n] = sum_e norm*T[src] + dis^2*T[n] (+bias,relu) ----
// One wave per node. Lanes 0-31 fetch even-offset records, lanes 32-63 odd;
// 4 records per half per iter -> 8 row-gathers in flight per wave.
template <bool RELU_BIAS>
__global__ __launch_bounds__(256) void k_gather64(const uint2* __restrict__ rec,
                                                  const int* __restrict__ rs,
                                                  const float* __restrict__ dis,
                                                  const float* __restrict__ T,
                                                  const float* __restrict__ bias,
                                                  float* __restrict__ out) {
    int wave = (blockIdx.x * 256 + threadIdx.x) >> 6;
    int lane = threadIdx.x & 63;
    int half = lane >> 5;
    int l    = lane & 31;         // float2 index within row
    if (wave >= N_NODES) return;
    int n = wave;
    int begin = (n == 0) ? 0 : rs[n - 1];   // post-build: rs[k] = end(k)
    int end = rs[n];
    const float2* T2 = (const float2*)T;

    float ax0 = 0.f, ay0 = 0.f, ax1 = 0.f, ay1 = 0.f;
    float ax2 = 0.f, ay2 = 0.f, ax3 = 0.f, ay3 = 0.f;
    int k = begin + half;
    while (k + 6 < end) {                   // 4 records per half per iter
        uint2 r0 = rec[k];
        uint2 r1 = rec[k + 2];
        uint2 r2 = rec[k + 4];
        uint2 r3 = rec[k + 6];
        float2 t0 = T2[(size_t)r0.x * 32 + l];
        float2 t1 = T2[(size_t)r1.x * 32 + l];
        float2 t2 = T2[(size_t)r2.x * 32 + l];
        float2 t3 = T2[(size_t)r3.x * 32 + l];
        float n0 = __uint_as_float(r0.y);
        float n1 = __uint_as_float(r1.y);
        float n2 = __uint_as_float(r2.y);
        float n3 = __uint_as_float(r3.y);
        ax0 += t0.x * n0; ay0 += t0.y * n0;
        ax1 += t1.x * n1; ay1 += t1.y * n1;
        ax2 += t2.x * n2; ay2 += t2.y * n2;
        ax3 += t3.x * n3; ay3 += t3.y * n3;
        k += 8;
    }
    while (k < end) {                       // remainder, 1 record per half
        uint2 r = rec[k];
        float2 t = T2[(size_t)r.x * 32 + l];
        float nn = __uint_as_float(r.y);
        ax0 += t.x * nn; ay0 += t.y * nn;
        k += 2;
    }
    float ax = (ax0 + ax1) + (ax2 + ax3);
    float ay = (ay0 + ay1) + (ay2 + ay3);
    if (half == 0) {                        // self-loop term, counted once
        float di = dis[n];
        float2 t = T2[(size_t)n * 32 + l];
        ax += t.x * di * di; ay += t.y * di * di;
    }
    ax += __shfl_xor(ax, 32, 64);           // combine halves
    ay += __shfl_xor(ay, 32, 64);
    if (half == 0) {
        if (RELU_BIAS) {
            const float2* B2 = (const float2*)bias;
            float2 b = B2[l];
            ax += b.x; ay += b.y;
            ax = ax > 0.f ? ax : 0.f;
            ay = ay > 0.f ? ay : 0.f;
        }
        ((float2*)out)[(size_t)n * 32 + l] = make_float2(ax, ay);
    }
}

// ---- fused: h2 = relu(agg2 @ W2 + b2); pool[batch] += h2 ----
// 64 contiguous nodes/block; thread (slice,colquad) walks 8 contiguous nodes,
// run-length accumulating the pooled sum in registers (batch is sorted),
// flushing atomics only on graph-id change.
__global__ __launch_bounds__(256) void k_gemm2_pool(const float* __restrict__ agg,
                                                    const float* __restrict__ W2,
                                                    const float* __restrict__ b2,
                                                    const int* __restrict__ batch,
                                                    float* __restrict__ pool) {
    __shared__ float Ws[HID * EMB];         // 32 KB
    __shared__ float as[NB2][HID];          // 16 KB (broadcast reads -> no conflict)
    __shared__ int   bs[NB2];
    int tid = threadIdx.x;
    const float4* W4 = (const float4*)W2;
    float4* Ws4 = (float4*)Ws;
    for (int i = tid; i < HID * EMB / 4; i += 256) Ws4[i] = W4[i];
    int base = blockIdx.x * NB2;
    const float4* A4 = (const float4*)agg;
    float4* as4 = (float4*)as;
    for (int i = tid; i < NB2 * HID / 4; i += 256) {       // 1024 float4, coalesced
        int node = base + (i >> 4);
        as4[i] = (node < N_NODES) ? A4[(size_t)node * 16 + (i & 15)]
                                  : make_float4(0.f, 0.f, 0.f, 0.f);
    }
    if (tid < NB2) {
        int node = base + tid;
        bs[tid] = (node < N_NODES) ? batch[node] : -1;
    }
    __syncthreads();

    int c = tid & 31;             // column-quad id (4 cols)
    int s = tid >> 5;             // node slice 0..7 (8 contiguous nodes each)
    int jc = c * 4;
    float4 bq = *(const float4*)&b2[jc];
    float4 racc = make_float4(0.f, 0.f, 0.f, 0.f);
    int gcur = -1;
    for (int ni = s * 8; ni < s * 8 + 8; ++ni) {
        int g = bs[ni];
        if (g != gcur) {
            if (gcur >= 0) {
                float* p = &pool[(size_t)gcur * EMB + jc];
                atomicAdd(p + 0, racc.x); atomicAdd(p + 1, racc.y);
                atomicAdd(p + 2, racc.z); atomicAdd(p + 3, racc.w);
            }
            racc = make_float4(0.f, 0.f, 0.f, 0.f);
            gcur = g;
        }
        if (g < 0) continue;
        float4 acc = bq;
        #pragma unroll 8
        for (int k = 0; k < HID; ++k) {
            float a = as[ni][k];               // wave-broadcast (2 addrs/wave: free)
            float4 w = Ws4[k * 32 + c];
            acc.x += a * w.x; acc.y += a * w.y; acc.z += a * w.z; acc.w += a * w.w;
        }
        racc.x += fmaxf(acc.x, 0.f);
        racc.y += fmaxf(acc.y, 0.f);
        racc.z += fmaxf(acc.z, 0.f);
        racc.w += fmaxf(acc.w, 0.f);
    }
    if (gcur >= 0) {
        float* p = &pool[(size_t)gcur * EMB + jc];
        atomicAdd(p + 0, racc.x); atomicAdd(p + 1, racc.y);
        atomicAdd(p + 2, racc.z); atomicAdd(p + 3, racc.w);
    }
}

__global__ void k_divide(const float* __restrict__ pool, const int* __restrict__ gstart,
                         float* __restrict__ out) {
    int idx = blockIdx.x * blockDim.x + threadIdx.x;
    if (idx >= N_GRAPHS * EMB) return;
    int g = idx >> 7;
    float c = (float)(gstart[g + 1] - gstart[g]);
    out[idx] = pool[idx] / fmaxf(c, 1.0f);
}

extern "C" void kernel_launch(void* const* d_in, const int* in_sizes, int n_in,
                              void* d_out, int out_size, void* d_ws, size_t ws_size,
                              hipStream_t stream) {
    const float* x     = (const float*)d_in[0];
    const int*   eidx  = (const int*)d_in[1];     // [2, E]: src then dst
    const float* ew    = (const float*)d_in[2];
    const int*   batch = (const int*)d_in[3];
    const float* W1    = (const float*)d_in[4];
    const float* b1    = (const float*)d_in[5];
    const float* W2    = (const float*)d_in[6];
    const float* b2    = (const float*)d_in[7];
    float* out = (float*)d_out;

    const int* src = eidx;
    const int* dst = eidx + N_EDGES;

    float* ws     = (float*)d_ws;
    float* deg    = ws + OFF_DEG;
    float* dis    = ws + OFF_DIS;
    float* pool   = ws + OFF_POOL;
    int*   gstart = (int*)(ws + OFF_GST);
    int*   hist   = (int*)(ws + OFF_HIST);
    int*   rs     = (int*)(ws + OFF_RS);
    int*   bsum   = (int*)(ws + OFF_BSUM);
    uint2* rec    = (uint2*)(ws + OFF_REC);
    float* h1     = ws + OFF_H1;
    float* h1p    = ws + OFF_H1P;
    float* agg2   = ws + OFF_AGG2;   // overlays h1p (dead after gather1)

    // Zero header region (deg, dis, pool, gstart, hist, rs, bsum) in one shot.
    hipMemsetAsync(ws, 0, OFF_REC * sizeof(float), stream);

    // Degree + histogram; dis; graph starts (boundary detection, no atomics).
    k_deg_hist<<<(N_EDGES + 255) / 256, 256, 0, stream>>>(dst, ew, deg, hist);
    k_dis<<<(N_NODES + 255) / 256, 256, 0, stream>>>(deg, dis);
    k_gstart<<<(N_NODES + 255) / 256, 256, 0, stream>>>(batch, gstart);

    // Exclusive scan of hist -> rs.
    k_scan1<<<NCHUNK, 256, 0, stream>>>(hist, bsum);
    k_scan2<<<1, 256, 0, stream>>>(bsum);
    k_scan3<<<NCHUNK, 256, 0, stream>>>(hist, bsum, rs);

    // Layer-1 linear (independent of CSR build).
    k_gemm1<<<N_NODES / 16, 256, 0, stream>>>(x, W1, h1p);

    // CSR build (rs[d] advances to end(d)).
    k_build<<<(N_EDGES + 255) / 256, 256, 0, stream>>>(src, dst, ew, dis, rs, rec);

    // Layer 1 aggregate + bias + relu (64-dim gather).
    k_gather64<true><<<N_NODES / 4, 256, 0, stream>>>(rec, rs, dis, h1p, b1, h1);

    // Layer 2 aggregate BEFORE the linear (Agg(h1@W2) == (Agg h1)@W2).
    k_gather64<false><<<N_NODES / 4, 256, 0, stream>>>(rec, rs, dis, h1, nullptr, agg2);

    // Fused layer-2 linear + relu + run-length pooled accumulate.
    k_gemm2_pool<<<(N_NODES + NB2 - 1) / NB2, 256, 0, stream>>>(agg2, W2, b2, batch, pool);

    k_divide<<<(N_GRAPHS * EMB + 255) / 256, 256, 0, stream>>>(pool, gstart, out);
}

// Round 6
// 308.134 us; speedup vs baseline: 3.1897x; 1.1277x over previous
//
#include <hip/hip_runtime.h>

// GCNEncoder round 6: round-5 structure +
//  (a) deg+hist fused into ONE u64 atomic per edge (count in bits>=40,
//      edge weight in 32.8 fixed point below — deg<256 so no carry),
//  (b) gemm1 co-dispatched with the atomic histogram as a heterogeneous grid
//      (atomics are TCC-latency-bound with idle VALU; gemm fills it),
//  (c) dis+hist-unpack+gstart fused into one elementwise kernel.
constexpr int N_NODES  = 50000;
constexpr int N_EDGES  = 800000;
constexpr int N_GRAPHS = 256;
constexpr int IN_DIM   = 128;
constexpr int HID      = 64;
constexpr int EMB      = 128;
constexpr int NCHUNK   = (N_NODES + 255) / 256;   // 196 scan chunks
constexpr int NB2      = 64;                      // nodes per gemm2_pool block
constexpr int HB       = (N_EDGES + 1023) / 1024; // 782 hist blocks (4 edges/thr)
constexpr int GB       = N_NODES / 16;            // 3125 gemm1 blocks

// Workspace layout in 4-byte units (33.1 MB total; 45.7 MB proven available).
constexpr size_t OFF_DEG64 = 0;                                   // u64 [50000]
constexpr size_t OFF_DIS   = 100000;                              // f32 [50000]
constexpr size_t OFF_POOL  = 150000;                              // f32 [256*128]
constexpr size_t OFF_GST   = OFF_POOL + (size_t)N_GRAPHS * EMB;   // i32 [257]
constexpr size_t OFF_HIST  = 183040;                              // i32 [50000]
constexpr size_t OFF_RS    = OFF_HIST + N_NODES;                  // i32 [50000]
constexpr size_t OFF_BSUM  = OFF_RS + N_NODES;                    // i32 [256]
constexpr size_t OFF_REC   = 283392;                              // uint2 [800000] (8B-aligned)
constexpr size_t OFF_H1    = OFF_REC + 2 * (size_t)N_EDGES;       // f32 [50000*64]
constexpr size_t OFF_H1P   = OFF_H1 + (size_t)N_NODES * HID;      // f32 [50000*64]
constexpr size_t OFF_AGG2  = OFF_H1P;  // f32 [50000*64]; overlays h1p (dead after gather1)

// ---- fused: [0,HB) blocks do u64 deg|hist atomics; [HB,HB+GB) do x@W1 ----
__global__ __launch_bounds__(256) void k_fused0(const int* __restrict__ dst,
                                                const float* __restrict__ ew,
                                                unsigned long long* __restrict__ deg64,
                                                const float* __restrict__ x,
                                                const float* __restrict__ W1,
                                                float* __restrict__ h) {
    __shared__ float Ws[IN_DIM * HID];      // 32 KB (gemm role only)
    __shared__ float xs[16][IN_DIM + 1];    // 8.25 KB, padded vs 4-way broadcast conflict
    int tid = threadIdx.x;
    if (blockIdx.x < HB) {
        int base = blockIdx.x * 1024;
        #pragma unroll
        for (int i = 0; i < 4; ++i) {
            int e = base + i * 256 + tid;
            if (e < N_EDGES) {
                // count in bits >=40; ew in 32-bit fixed point (deg<256 => no carry)
                unsigned long long p = (1ull << 40)
                    | (unsigned long long)(ew[e] * 4294967296.0f + 0.5f);
                atomicAdd(&deg64[dst[e]], p);
            }
        }
        return;
    }
    // ---- gemm1 role: 16 nodes/block, 16 thr x float4 per node ----
    int bid = blockIdx.x - HB;
    const float4* W4 = (const float4*)W1;
    float4* Ws4 = (float4*)Ws;
    for (int i = tid; i < IN_DIM * HID / 4; i += 256) Ws4[i] = W4[i];
    int base = bid * 16;
    for (int i = tid; i < 16 * IN_DIM; i += 256) {
        int ln = i >> 7, k = i & 127;
        xs[ln][k] = x[(size_t)(base + ln) * IN_DIM + k];
    }
    __syncthreads();
    int ln = tid >> 4;            // node in block
    int jc = (tid & 15) * 4;      // column base
    float4 acc = make_float4(0.f, 0.f, 0.f, 0.f);
    #pragma unroll 4
    for (int k = 0; k < IN_DIM; ++k) {
        float a = xs[ln][k];
        float4 w = *(const float4*)&Ws[k * HID + jc];
        acc.x += a * w.x; acc.y += a * w.y; acc.z += a * w.z; acc.w += a * w.w;
    }
    *(float4*)&h[(size_t)(base + ln) * HID + jc] = acc;
}

// ---- unpack deg64 -> hist, dis; sorted-batch boundary detection -> gstart ----
__global__ void k_dis_gstart(const unsigned long long* __restrict__ deg64,
                             float* __restrict__ dis, int* __restrict__ hist,
                             const int* __restrict__ batch, int* __restrict__ gstart) {
    int i = blockIdx.x * blockDim.x + threadIdx.x;
    if (i >= N_NODES) return;
    unsigned long long v = deg64[i];
    hist[i] = (int)(v >> 40);
    float d = (float)(v & 0xFFFFFFFFFFull) * (1.0f / 4294967296.0f) + 1.0f; // + self-loop
    dis[i] = rsqrtf(d);
    int g = batch[i];
    if (i == 0) {
        for (int gg = 0; gg <= g; ++gg) gstart[gg] = 0;
    } else {
        int gp = batch[i - 1];
        for (int gg = gp + 1; gg <= g; ++gg) gstart[gg] = i;
    }
    if (i == N_NODES - 1) {
        for (int gg = g + 1; gg <= N_GRAPHS; ++gg) gstart[gg] = N_NODES;
    }
}

// ---- exclusive scan of hist[50000] -> rs ----
__global__ __launch_bounds__(256) void k_scan1(const int* __restrict__ hist,
                                               int* __restrict__ bsum) {
    __shared__ int tmp[256];
    int t = threadIdx.x;
    int idx = blockIdx.x * 256 + t;
    tmp[t] = (idx < N_NODES) ? hist[idx] : 0;
    __syncthreads();
    for (int off = 128; off > 0; off >>= 1) {
        if (t < off) tmp[t] += tmp[t + off];
        __syncthreads();
    }
    if (t == 0) bsum[blockIdx.x] = tmp[0];
}

__global__ __launch_bounds__(256) void k_scan2(int* __restrict__ bsum) {
    __shared__ int tmp[256];
    int t = threadIdx.x;
    int v = (t < NCHUNK) ? bsum[t] : 0;
    tmp[t] = v;
    __syncthreads();
    for (int off = 1; off < 256; off <<= 1) {
        int add = (t >= off) ? tmp[t - off] : 0;
        __syncthreads();
        tmp[t] += add;
        __syncthreads();
    }
    if (t < NCHUNK) bsum[t] = tmp[t] - v;   // exclusive
}

__global__ __launch_bounds__(256) void k_scan3(const int* __restrict__ hist,
                                               const int* __restrict__ bsum,
                                               int* __restrict__ rs) {
    __shared__ int tmp[256];
    int t = threadIdx.x;
    int idx = blockIdx.x * 256 + t;
    int v = (idx < N_NODES) ? hist[idx] : 0;
    tmp[t] = v;
    __syncthreads();
    for (int off = 1; off < 256; off <<= 1) {
        int add = (t >= off) ? tmp[t - off] : 0;
        __syncthreads();
        tmp[t] += add;
        __syncthreads();
    }
    if (idx < N_NODES) rs[idx] = bsum[blockIdx.x] + tmp[t] - v;   // exclusive start
}

// ---- CSR build: rec[pos] = (src, norm); rs[d] advances to end(d) ----
__global__ void k_build(const int* __restrict__ src, const int* __restrict__ dst,
                        const float* __restrict__ ew, const float* __restrict__ dis,
                        int* __restrict__ rs, uint2* __restrict__ rec) {
    int e = blockIdx.x * blockDim.x + threadIdx.x;
    if (e >= N_EDGES) return;
    int s = src[e], d = dst[e];
    float norm = dis[s] * ew[e] * dis[d];
    int pos = atomicAdd(&rs[d], 1);
    rec[pos] = make_uint2((unsigned)s, __float_as_uint(norm));
}

// ---- 64-dim CSR gather: out[n] = sum_e norm*T[src] + dis^2*T[n] (+bias,relu) ----
// One wave per node. Lanes 0-31 fetch even-offset records, lanes 32-63 odd;
// 4 records per half per iter -> 8 row-gathers in flight per wave.
template <bool RELU_BIAS>
__global__ __launch_bounds__(256) void k_gather64(const uint2* __restrict__ rec,
                                                  const int* __restrict__ rs,
                                                  const float* __restrict__ dis,
                                                  const float* __restrict__ T,
                                                  const float* __restrict__ bias,
                                                  float* __restrict__ out) {
    int wave = (blockIdx.x * 256 + threadIdx.x) >> 6;
    int lane = threadIdx.x & 63;
    int half = lane >> 5;
    int l    = lane & 31;         // float2 index within row
    if (wave >= N_NODES) return;
    int n = wave;
    int begin = (n == 0) ? 0 : rs[n - 1];   // post-build: rs[k] = end(k)
    int end = rs[n];
    const float2* T2 = (const float2*)T;

    float ax0 = 0.f, ay0 = 0.f, ax1 = 0.f, ay1 = 0.f;
    float ax2 = 0.f, ay2 = 0.f, ax3 = 0.f, ay3 = 0.f;
    int k = begin + half;
    while (k + 6 < end) {                   // 4 records per half per iter
        uint2 r0 = rec[k];
        uint2 r1 = rec[k + 2];
        uint2 r2 = rec[k + 4];
        uint2 r3 = rec[k + 6];
        float2 t0 = T2[(size_t)r0.x * 32 + l];
        float2 t1 = T2[(size_t)r1.x * 32 + l];
        float2 t2 = T2[(size_t)r2.x * 32 + l];
        float2 t3 = T2[(size_t)r3.x * 32 + l];
        float n0 = __uint_as_float(r0.y);
        float n1 = __uint_as_float(r1.y);
        float n2 = __uint_as_float(r2.y);
        float n3 = __uint_as_float(r3.y);
        ax0 += t0.x * n0; ay0 += t0.y * n0;
        ax1 += t1.x * n1; ay1 += t1.y * n1;
        ax2 += t2.x * n2; ay2 += t2.y * n2;
        ax3 += t3.x * n3; ay3 += t3.y * n3;
        k += 8;
    }
    while (k < end) {                       // remainder, 1 record per half
        uint2 r = rec[k];
        float2 t = T2[(size_t)r.x * 32 + l];
        float nn = __uint_as_float(r.y);
        ax0 += t.x * nn; ay0 += t.y * nn;
        k += 2;
    }
    float ax = (ax0 + ax1) + (ax2 + ax3);
    float ay = (ay0 + ay1) + (ay2 + ay3);
    if (half == 0) {                        // self-loop term, counted once
        float di = dis[n];
        float2 t = T2[(size_t)n * 32 + l];
        ax += t.x * di * di; ay += t.y * di * di;
    }
    ax += __shfl_xor(ax, 32, 64);           // combine halves
    ay += __shfl_xor(ay, 32, 64);
    if (half == 0) {
        if (RELU_BIAS) {
            const float2* B2 = (const float2*)bias;
            float2 b = B2[l];
            ax += b.x; ay += b.y;
            ax = ax > 0.f ? ax : 0.f;
            ay = ay > 0.f ? ay : 0.f;
        }
        ((float2*)out)[(size_t)n * 32 + l] = make_float2(ax, ay);
    }
}

// ---- fused: h2 = relu(agg2 @ W2 + b2); pool[batch] += h2 ----
// 64 contiguous nodes/block; thread (slice,colquad) walks 8 contiguous nodes,
// run-length accumulating the pooled sum in registers (batch is sorted),
// flushing atomics only on graph-id change.
__global__ __launch_bounds__(256) void k_gemm2_pool(const float* __restrict__ agg,
                                                    const float* __restrict__ W2,
                                                    const float* __restrict__ b2,
                                                    const int* __restrict__ batch,
                                                    float* __restrict__ pool) {
    __shared__ float Ws[HID * EMB];         // 32 KB
    __shared__ float as[NB2][HID];          // 16 KB (broadcast reads -> no conflict)
    __shared__ int   bs[NB2];
    int tid = threadIdx.x;
    const float4* W4 = (const float4*)W2;
    float4* Ws4 = (float4*)Ws;
    for (int i = tid; i < HID * EMB / 4; i += 256) Ws4[i] = W4[i];
    int base = blockIdx.x * NB2;
    const float4* A4 = (const float4*)agg;
    float4* as4 = (float4*)as;
    for (int i = tid; i < NB2 * HID / 4; i += 256) {       // 1024 float4, coalesced
        int node = base + (i >> 4);
        as4[i] = (node < N_NODES) ? A4[(size_t)node * 16 + (i & 15)]
                                  : make_float4(0.f, 0.f, 0.f, 0.f);
    }
    if (tid < NB2) {
        int node = base + tid;
        bs[tid] = (node < N_NODES) ? batch[node] : -1;
    }
    __syncthreads();

    int c = tid & 31;             // column-quad id (4 cols)
    int s = tid >> 5;             // node slice 0..7 (8 contiguous nodes each)
    int jc = c * 4;
    float4 bq = *(const float4*)&b2[jc];
    float4 racc = make_float4(0.f, 0.f, 0.f, 0.f);
    int gcur = -1;
    for (int ni = s * 8; ni < s * 8 + 8; ++ni) {
        int g = bs[ni];
        if (g != gcur) {
            if (gcur >= 0) {
                float* p = &pool[(size_t)gcur * EMB + jc];
                atomicAdd(p + 0, racc.x); atomicAdd(p + 1, racc.y);
                atomicAdd(p + 2, racc.z); atomicAdd(p + 3, racc.w);
            }
            racc = make_float4(0.f, 0.f, 0.f, 0.f);
            gcur = g;
        }
        if (g < 0) continue;
        float4 acc = bq;
        #pragma unroll 8
        for (int k = 0; k < HID; ++k) {
            float a = as[ni][k];               // wave-broadcast (2 addrs/wave: free)
            float4 w = Ws4[k * 32 + c];
            acc.x += a * w.x; acc.y += a * w.y; acc.z += a * w.z; acc.w += a * w.w;
        }
        racc.x += fmaxf(acc.x, 0.f);
        racc.y += fmaxf(acc.y, 0.f);
        racc.z += fmaxf(acc.z, 0.f);
        racc.w += fmaxf(acc.w, 0.f);
    }
    if (gcur >= 0) {
        float* p = &pool[(size_t)gcur * EMB + jc];
        atomicAdd(p + 0, racc.x); atomicAdd(p + 1, racc.y);
        atomicAdd(p + 2, racc.z); atomicAdd(p + 3, racc.w);
    }
}

__global__ void k_divide(const float* __restrict__ pool, const int* __restrict__ gstart,
                         float* __restrict__ out) {
    int idx = blockIdx.x * blockDim.x + threadIdx.x;
    if (idx >= N_GRAPHS * EMB) return;
    int g = idx >> 7;
    float c = (float)(gstart[g + 1] - gstart[g]);
    out[idx] = pool[idx] / fmaxf(c, 1.0f);
}

extern "C" void kernel_launch(void* const* d_in, const int* in_sizes, int n_in,
                              void* d_out, int out_size, void* d_ws, size_t ws_size,
                              hipStream_t stream) {
    const float* x     = (const float*)d_in[0];
    const int*   eidx  = (const int*)d_in[1];     // [2, E]: src then dst
    const float* ew    = (const float*)d_in[2];
    const int*   batch = (const int*)d_in[3];
    const float* W1    = (const float*)d_in[4];
    const float* b1    = (const float*)d_in[5];
    const float* W2    = (const float*)d_in[6];
    const float* b2    = (const float*)d_in[7];
    float* out = (float*)d_out;

    const int* src = eidx;
    const int* dst = eidx + N_EDGES;

    float* ws     = (float*)d_ws;
    unsigned long long* deg64 = (unsigned long long*)(ws + OFF_DEG64);
    float* dis    = ws + OFF_DIS;
    float* pool   = ws + OFF_POOL;
    int*   gstart = (int*)(ws + OFF_GST);
    int*   hist   = (int*)(ws + OFF_HIST);
    int*   rs     = (int*)(ws + OFF_RS);
    int*   bsum   = (int*)(ws + OFF_BSUM);
    uint2* rec    = (uint2*)(ws + OFF_REC);
    float* h1     = ws + OFF_H1;
    float* h1p    = ws + OFF_H1P;
    float* agg2   = ws + OFF_AGG2;   // overlays h1p (dead after gather1)

    // Zero deg64 + pool (+dis/gstart incidentally) in one shot.
    hipMemsetAsync(ws, 0, OFF_HIST * sizeof(float), stream);

    // Fused: u64 deg|hist atomics (latency-bound) + gemm1 (VALU-bound) co-dispatch.
    k_fused0<<<HB + GB, 256, 0, stream>>>(dst, ew, deg64, x, W1, h1p);

    // Unpack hist/dis + graph starts.
    k_dis_gstart<<<(N_NODES + 255) / 256, 256, 0, stream>>>(deg64, dis, hist, batch, gstart);

    // Exclusive scan of hist -> rs.
    k_scan1<<<NCHUNK, 256, 0, stream>>>(hist, bsum);
    k_scan2<<<1, 256, 0, stream>>>(bsum);
    k_scan3<<<NCHUNK, 256, 0, stream>>>(hist, bsum, rs);

    // CSR build (rs[d] advances to end(d)).
    k_build<<<(N_EDGES + 255) / 256, 256, 0, stream>>>(src, dst, ew, dis, rs, rec);

    // Layer 1 aggregate + bias + relu (64-dim gather).
    k_gather64<true><<<N_NODES / 4, 256, 0, stream>>>(rec, rs, dis, h1p, b1, h1);

    // Layer 2 aggregate BEFORE the linear (Agg(h1@W2) == (Agg h1)@W2).
    k_gather64<false><<<N_NODES / 4, 256, 0, stream>>>(rec, rs, dis, h1, nullptr, agg2);

    // Fused layer-2 linear + relu + run-length pooled accumulate.
    k_gemm2_pool<<<(N_NODES + NB2 - 1) / NB2, 256, 0, stream>>>(agg2, W2, b2, batch, pool);

    k_divide<<<(N_GRAPHS * EMB + 255) / 256, 256, 0, stream>>>(pool, gstart, out);
}

// Round 7
// 281.151 us; speedup vs baseline: 3.4959x; 1.0960x over previous
//
#include <hip/hip_runtime.h>

// GCNEncoder round 7: random GLOBAL atomics eliminated entirely.
// CSR built by 2-pass bucket counting sort (bucket = dst>>8, 196 buckets);
// all histogram/rank atomics are LDS-local. Degree summed exactly in LDS.
// Gathers apply norm on the fly: per-record dis[src] broadcast load,
// wave-uniform dis[n] factored into one final multiply.
constexpr int N_NODES  = 50000;
constexpr int N_EDGES  = 800000;
constexpr int N_GRAPHS = 256;
constexpr int IN_DIM   = 128;
constexpr int HID      = 64;
constexpr int EMB      = 128;
constexpr int NBKT     = 196;                       // buckets: dst>>8, 50000/256
constexpr int EB       = (N_EDGES + 1023) / 1024;   // 782 edge blocks (1024 edges each)
constexpr int GB       = N_NODES / 16;              // 3125 gemm1 blocks
constexpr int GSB      = (N_NODES + 255) / 256;     // 196 gstart blocks
constexpr int NB2      = 64;                        // nodes per gemm2_pool block

// Workspace layout in 4-byte units (~33.1 MB; 45.7 MB proven available).
constexpr size_t OFF_POOL  = 0;                                 // f32 [256*128]
constexpr size_t OFF_GST   = 32768;                             // i32 [257]
constexpr size_t OFF_BBASE = 33026;                             // i32 [197]
constexpr size_t OFF_DIS   = 33224;                             // f32 [50000]
constexpr size_t OFF_RS    = 83224;                             // i32 [50000]
constexpr size_t OFF_HCNT  = 133224;                            // i32 [782*196]
constexpr size_t OFF_REC   = 286496;                            // uint2 [800000]
constexpr size_t OFF_PART  = OFF_REC + 2 * (size_t)N_EDGES;     // uint4 [800000] (16B-aligned)
constexpr size_t OFF_H1    = OFF_PART;  // f32 [50000*64]; overlays part (dead after P3)
constexpr size_t OFF_H1P   = OFF_PART + 4 * (size_t)N_EDGES;    // f32 [50000*64]
constexpr size_t OFF_AGG2  = OFF_H1P;   // f32 [50000*64]; overlays h1p (dead after gather1)

// ---- P1: per-block bucket histogram (LDS atomics only) ----
__global__ __launch_bounds__(256) void k_p1(const int* __restrict__ dst,
                                            int* __restrict__ hcnt) {
    __shared__ int lh[NBKT];
    int tid = threadIdx.x;
    for (int i = tid; i < NBKT; i += 256) lh[i] = 0;
    __syncthreads();
    int base = blockIdx.x * 1024;
    #pragma unroll
    for (int j = 0; j < 4; ++j) {
        int e = base + j * 256 + tid;
        if (e < N_EDGES) atomicAdd(&lh[dst[e] >> 8], 1);
    }
    __syncthreads();
    for (int i = tid; i < NBKT; i += 256) hcnt[blockIdx.x * NBKT + i] = lh[i];
}

// ---- KAB: bucket totals + exclusive scan -> bbase[197] (one block) ----
__global__ __launch_bounds__(256) void k_kab(const int* __restrict__ hcnt,
                                             int* __restrict__ bbase) {
    __shared__ int tile[256];
    int t = threadIdx.x;
    int v = 0;
    if (t < NBKT) {
        for (int i = 0; i < EB; ++i) v += hcnt[i * NBKT + t];
    }
    tile[t] = v;
    __syncthreads();
    for (int off = 1; off < 256; off <<= 1) {
        int a = (t >= off) ? tile[t - off] : 0;
        __syncthreads();
        tile[t] += a;
        __syncthreads();
    }
    if (t < NBKT) bbase[t] = tile[t] - v;       // exclusive
    if (t == NBKT - 1) bbase[NBKT] = tile[t];   // total = N_EDGES
}

// ---- KC: per-bucket column scan of hcnt in place (+ gstart role) ----
__global__ __launch_bounds__(256) void k_kc(int* __restrict__ hcnt,
                                            const int* __restrict__ bbase,
                                            const int* __restrict__ batch,
                                            int* __restrict__ gstart) {
    __shared__ int tile[256];
    __shared__ int carry;
    int t = threadIdx.x;
    if (blockIdx.x < NBKT) {
        int b = blockIdx.x;
        if (t == 0) carry = bbase[b];
        __syncthreads();
        for (int i0 = 0; i0 < EB; i0 += 256) {
            int i = i0 + t;
            int v = (i < EB) ? hcnt[i * NBKT + b] : 0;
            tile[t] = v;
            __syncthreads();
            for (int off = 1; off < 256; off <<= 1) {
                int a = (t >= off) ? tile[t - off] : 0;
                __syncthreads();
                tile[t] += a;
                __syncthreads();
            }
            int incl = tile[t];
            if (i < EB) hcnt[i * NBKT + b] = carry + incl - v;   // exclusive + carry
            __syncthreads();
            if (t == 255) carry += incl;
            __syncthreads();
        }
        return;
    }
    // ---- gstart role: sorted-batch boundary detection ----
    int i = (blockIdx.x - NBKT) * 256 + t;
    if (i >= N_NODES) return;
    int g = batch[i];
    if (i == 0) {
        for (int gg = 0; gg <= g; ++gg) gstart[gg] = 0;
    } else {
        int gp = batch[i - 1];
        for (int gg = gp + 1; gg <= g; ++gg) gstart[gg] = i;
    }
    if (i == N_NODES - 1) {
        for (int gg = g + 1; gg <= N_GRAPHS; ++gg) gstart[gg] = N_NODES;
    }
}

// ---- P2: partition edges into buckets (LDS cursors, no global atomics) ----
__global__ __launch_bounds__(256) void k_p2(const int* __restrict__ src,
                                            const int* __restrict__ dst,
                                            const float* __restrict__ ew,
                                            const int* __restrict__ hcnt,
                                            uint4* __restrict__ part) {
    __shared__ int lb[NBKT];
    __shared__ int lc[NBKT];
    int tid = threadIdx.x;
    for (int i = tid; i < NBKT; i += 256) {
        lb[i] = hcnt[blockIdx.x * NBKT + i];
        lc[i] = 0;
    }
    __syncthreads();
    int base = blockIdx.x * 1024;
    #pragma unroll
    for (int j = 0; j < 4; ++j) {
        int e = base + j * 256 + tid;
        if (e < N_EDGES) {
            int d = dst[e];
            int b = d >> 8;
            int r = atomicAdd(&lc[b], 1);
            part[lb[b] + r] = make_uint4((unsigned)src[e], (unsigned)d,
                                         __float_as_uint(ew[e]), 0u);
        }
    }
}

// ---- P3 (+gemm1 het-fused): per-bucket CSR finalize + degree + dis ----
// blocks [0,NBKT): bucket b = 256 contiguous nodes; LDS count + LDS f32 degree
// sum, block scan -> rs (end pointers, continuous across buckets), dis,
// LDS-cursor scatter -> rec=(src, ew_bits).
// blocks [NBKT, NBKT+GB): h1p = x @ W1 (16 nodes/block, 16 thr x float4).
__global__ __launch_bounds__(256) void k_p3_gemm1(const uint4* __restrict__ part,
                                                  const int* __restrict__ bbase,
                                                  int* __restrict__ rs,
                                                  float* __restrict__ dis,
                                                  uint2* __restrict__ rec,
                                                  const float* __restrict__ x,
                                                  const float* __restrict__ W1,
                                                  float* __restrict__ h) {
    __shared__ float Ws[IN_DIM * HID];      // 32 KB (gemm role)
    __shared__ float xs[16][IN_DIM + 1];    // 8.25 KB (gemm role)
    __shared__ int   cnt[256];
    __shared__ float dgw[256];
    __shared__ int   scn[256];
    __shared__ int   cur[256];
    int tid = threadIdx.x;
    if (blockIdx.x < NBKT) {
        int b = blockIdx.x;
        int base_node = b << 8;
        int ebeg = bbase[b], eend = bbase[b + 1];
        cnt[tid] = 0;
        dgw[tid] = 0.f;
        __syncthreads();
        for (int e = ebeg + tid; e < eend; e += 256) {
            uint4 r = part[e];
            int ld = (int)r.y & 255;
            atomicAdd(&cnt[ld], 1);
            atomicAdd(&dgw[ld], __uint_as_float(r.z));
        }
        __syncthreads();
        scn[tid] = cnt[tid];
        __syncthreads();
        for (int off = 1; off < 256; off <<= 1) {
            int a = (tid >= off) ? scn[tid - off] : 0;
            __syncthreads();
            scn[tid] += a;
            __syncthreads();
        }
        int node = base_node + tid;
        if (node < N_NODES) {
            rs[node] = ebeg + scn[tid];                 // end pointer
            dis[node] = rsqrtf(dgw[tid] + 1.0f);        // + self-loop weight 1
        }
        cur[tid] = ebeg + scn[tid] - cnt[tid];          // row start cursor
        __syncthreads();
        for (int e = ebeg + tid; e < eend; e += 256) {
            uint4 r = part[e];
            int ld = (int)r.y & 255;
            int pos = atomicAdd(&cur[ld], 1);
            rec[pos] = make_uint2(r.x, r.z);            // (src, ew_bits)
        }
        return;
    }
    // ---- gemm1 role ----
    int bid = blockIdx.x - NBKT;
    const float4* W4 = (const float4*)W1;
    float4* Ws4 = (float4*)Ws;
    for (int i = tid; i < IN_DIM * HID / 4; i += 256) Ws4[i] = W4[i];
    int base = bid * 16;
    for (int i = tid; i < 16 * IN_DIM; i += 256) {
        int ln = i >> 7, k = i & 127;
        xs[ln][k] = x[(size_t)(base + ln) * IN_DIM + k];
    }
    __syncthreads();
    int ln = tid >> 4;
    int jc = (tid & 15) * 4;
    float4 acc = make_float4(0.f, 0.f, 0.f, 0.f);
    #pragma unroll 4
    for (int k = 0; k < IN_DIM; ++k) {
        float a = xs[ln][k];
        float4 w = *(const float4*)&Ws[k * HID + jc];
        acc.x += a * w.x; acc.y += a * w.y; acc.z += a * w.z; acc.w += a * w.w;
    }
    *(float4*)&h[(size_t)(base + ln) * HID + jc] = acc;
}

// ---- 64-dim CSR gather: out[n] = dis[n]*(sum_e dis[s]*ew*T[s] + dis[n]*T[n]) ----
// One wave per node; halves interleave records; 4 records/half in flight.
template <bool RELU_BIAS>
__global__ __launch_bounds__(256) void k_gather64(const uint2* __restrict__ rec,
                                                  const int* __restrict__ rs,
                                                  const float* __restrict__ dis,
                                                  const float* __restrict__ T,
                                                  const float* __restrict__ bias,
                                                  float* __restrict__ out) {
    int wave = (blockIdx.x * 256 + threadIdx.x) >> 6;
    int lane = threadIdx.x & 63;
    int half = lane >> 5;
    int l    = lane & 31;         // float2 index within row
    if (wave >= N_NODES) return;
    int n = wave;
    int begin = (n == 0) ? 0 : rs[n - 1];
    int end = rs[n];
    const float2* T2 = (const float2*)T;

    float ax0 = 0.f, ay0 = 0.f, ax1 = 0.f, ay1 = 0.f;
    float ax2 = 0.f, ay2 = 0.f, ax3 = 0.f, ay3 = 0.f;
    int k = begin + half;
    while (k + 6 < end) {                   // 4 records per half per iter
        uint2 r0 = rec[k];
        uint2 r1 = rec[k + 2];
        uint2 r2 = rec[k + 4];
        uint2 r3 = rec[k + 6];
        float d0 = dis[r0.x];
        float d1 = dis[r1.x];
        float d2 = dis[r2.x];
        float d3 = dis[r3.x];
        float2 t0 = T2[(size_t)r0.x * 32 + l];
        float2 t1 = T2[(size_t)r1.x * 32 + l];
        float2 t2 = T2[(size_t)r2.x * 32 + l];
        float2 t3 = T2[(size_t)r3.x * 32 + l];
        float n0 = d0 * __uint_as_float(r0.y);
        float n1 = d1 * __uint_as_float(r1.y);
        float n2 = d2 * __uint_as_float(r2.y);
        float n3 = d3 * __uint_as_float(r3.y);
        ax0 += t0.x * n0; ay0 += t0.y * n0;
        ax1 += t1.x * n1; ay1 += t1.y * n1;
        ax2 += t2.x * n2; ay2 += t2.y * n2;
        ax3 += t3.x * n3; ay3 += t3.y * n3;
        k += 8;
    }
    while (k < end) {                       // remainder
        uint2 r = rec[k];
        float nn = dis[r.x] * __uint_as_float(r.y);
        float2 t = T2[(size_t)r.x * 32 + l];
        ax0 += t.x * nn; ay0 += t.y * nn;
        k += 2;
    }
    float ax = (ax0 + ax1) + (ax2 + ax3);
    float ay = (ay0 + ay1) + (ay2 + ay3);
    float di = dis[n];
    if (half == 0) {                        // self-loop (pre-factored form)
        float2 t = T2[(size_t)n * 32 + l];
        ax += t.x * di; ay += t.y * di;
    }
    ax += __shfl_xor(ax, 32, 64);           // combine halves
    ay += __shfl_xor(ay, 32, 64);
    if (half == 0) {
        ax *= di; ay *= di;                 // wave-uniform dis[n] factor
        if (RELU_BIAS) {
            const float2* B2 = (const float2*)bias;
            float2 b = B2[l];
            ax += b.x; ay += b.y;
            ax = ax > 0.f ? ax : 0.f;
            ay = ay > 0.f ? ay : 0.f;
        }
        ((float2*)out)[(size_t)n * 32 + l] = make_float2(ax, ay);
    }
}

// ---- fused: h2 = relu(agg2 @ W2 + b2); pool[batch] += h2 (run-length) ----
__global__ __launch_bounds__(256) void k_gemm2_pool(const float* __restrict__ agg,
                                                    const float* __restrict__ W2,
                                                    const float* __restrict__ b2,
                                                    const int* __restrict__ batch,
                                                    float* __restrict__ pool) {
    __shared__ float Ws[HID * EMB];         // 32 KB
    __shared__ float as[NB2][HID];          // 16 KB (broadcast reads)
    __shared__ int   bs[NB2];
    int tid = threadIdx.x;
    const float4* W4 = (const float4*)W2;
    float4* Ws4 = (float4*)Ws;
    for (int i = tid; i < HID * EMB / 4; i += 256) Ws4[i] = W4[i];
    int base = blockIdx.x * NB2;
    const float4* A4 = (const float4*)agg;
    float4* as4 = (float4*)as;
    for (int i = tid; i < NB2 * HID / 4; i += 256) {
        int node = base + (i >> 4);
        as4[i] = (node < N_NODES) ? A4[(size_t)node * 16 + (i & 15)]
                                  : make_float4(0.f, 0.f, 0.f, 0.f);
    }
    if (tid < NB2) {
        int node = base + tid;
        bs[tid] = (node < N_NODES) ? batch[node] : -1;
    }
    __syncthreads();

    int c = tid & 31;
    int s = tid >> 5;
    int jc = c * 4;
    float4 bq = *(const float4*)&b2[jc];
    float4 racc = make_float4(0.f, 0.f, 0.f, 0.f);
    int gcur = -1;
    for (int ni = s * 8; ni < s * 8 + 8; ++ni) {
        int g = bs[ni];
        if (g != gcur) {
            if (gcur >= 0) {
                float* p = &pool[(size_t)gcur * EMB + jc];
                atomicAdd(p + 0, racc.x); atomicAdd(p + 1, racc.y);
                atomicAdd(p + 2, racc.z); atomicAdd(p + 3, racc.w);
            }
            racc = make_float4(0.f, 0.f, 0.f, 0.f);
            gcur = g;
        }
        if (g < 0) continue;
        float4 acc = bq;
        #pragma unroll 8
        for (int k = 0; k < HID; ++k) {
            float a = as[ni][k];
            float4 w = Ws4[k * 32 + c];
            acc.x += a * w.x; acc.y += a * w.y; acc.z += a * w.z; acc.w += a * w.w;
        }
        racc.x += fmaxf(acc.x, 0.f);
        racc.y += fmaxf(acc.y, 0.f);
        racc.z += fmaxf(acc.z, 0.f);
        racc.w += fmaxf(acc.w, 0.f);
    }
    if (gcur >= 0) {
        float* p = &pool[(size_t)gcur * EMB + jc];
        atomicAdd(p + 0, racc.x); atomicAdd(p + 1, racc.y);
        atomicAdd(p + 2, racc.z); atomicAdd(p + 3, racc.w);
    }
}

__global__ void k_divide(const float* __restrict__ pool, const int* __restrict__ gstart,
                         float* __restrict__ out) {
    int idx = blockIdx.x * blockDim.x + threadIdx.x;
    if (idx >= N_GRAPHS * EMB) return;
    int g = idx >> 7;
    float c = (float)(gstart[g + 1] - gstart[g]);
    out[idx] = pool[idx] / fmaxf(c, 1.0f);
}

extern "C" void kernel_launch(void* const* d_in, const int* in_sizes, int n_in,
                              void* d_out, int out_size, void* d_ws, size_t ws_size,
                              hipStream_t stream) {
    const float* x     = (const float*)d_in[0];
    const int*   eidx  = (const int*)d_in[1];     // [2, E]: src then dst
    const float* ew    = (const float*)d_in[2];
    const int*   batch = (const int*)d_in[3];
    const float* W1    = (const float*)d_in[4];
    const float* b1    = (const float*)d_in[5];
    const float* W2    = (const float*)d_in[6];
    const float* b2    = (const float*)d_in[7];
    float* out = (float*)d_out;

    const int* src = eidx;
    const int* dst = eidx + N_EDGES;

    float* ws     = (float*)d_ws;
    float* pool   = ws + OFF_POOL;
    int*   gstart = (int*)(ws + OFF_GST);
    int*   bbase  = (int*)(ws + OFF_BBASE);
    float* dis    = ws + OFF_DIS;
    int*   rs     = (int*)(ws + OFF_RS);
    int*   hcnt   = (int*)(ws + OFF_HCNT);
    uint2* rec    = (uint2*)(ws + OFF_REC);
    uint4* part   = (uint4*)(ws + OFF_PART);
    float* h1     = ws + OFF_H1;    // overlays part (dead after P3)
    float* h1p    = ws + OFF_H1P;
    float* agg2   = ws + OFF_AGG2;  // overlays h1p (dead after gather1)

    // Only pool needs zeroing (everything else fully written).
    hipMemsetAsync(pool, 0, (size_t)N_GRAPHS * EMB * sizeof(float), stream);

    // Bucket counting sort (no global atomics anywhere).
    k_p1<<<EB, 256, 0, stream>>>(dst, hcnt);
    k_kab<<<1, 256, 0, stream>>>(hcnt, bbase);
    k_kc<<<NBKT + GSB, 256, 0, stream>>>(hcnt, bbase, batch, gstart);
    k_p2<<<EB, 256, 0, stream>>>(src, dst, ew, hcnt, part);

    // Per-bucket CSR finalize + degree/dis, het-fused with layer-1 linear.
    k_p3_gemm1<<<NBKT + GB, 256, 0, stream>>>(part, bbase, rs, dis, rec, x, W1, h1p);

    // Layer 1 aggregate + bias + relu (64-dim gather).
    k_gather64<true><<<N_NODES / 4, 256, 0, stream>>>(rec, rs, dis, h1p, b1, h1);

    // Layer 2 aggregate BEFORE the linear (Agg(h1@W2) == (Agg h1)@W2).
    k_gather64<false><<<N_NODES / 4, 256, 0, stream>>>(rec, rs, dis, h1, nullptr, agg2);

    // Fused layer-2 linear + relu + run-length pooled accumulate.
    k_gemm2_pool<<<(N_NODES + NB2 - 1) / NB2, 256, 0, stream>>>(agg2, W2, b2, batch, pool);

    k_divide<<<(N_GRAPHS * EMB + 255) / 256, 256, 0, stream>>>(pool, gstart, out);
}

// Round 9
// 259.934 us; speedup vs baseline: 3.7812x; 1.0816x over previous
//
#include <hip/hip_runtime.h>

// GCNEncoder round 9 (= round 8 with the FMA4 macro/.w collision fixed):
// bf16-packed gather tables (h1p, h1) to halve random-gather bytes and double
// per-XCD L2 residency, + register-blocked gemm1 (2 nodes x 4 cols / thread).
// CSR built by 2-pass bucket counting sort with LDS-only atomics.
constexpr int N_NODES  = 50000;
constexpr int N_EDGES  = 800000;
constexpr int N_GRAPHS = 256;
constexpr int IN_DIM   = 128;
constexpr int HID      = 64;
constexpr int EMB      = 128;
constexpr int NBKT     = 196;                       // buckets: dst>>8
constexpr int EB       = (N_EDGES + 1023) / 1024;   // 782 edge blocks
constexpr int GB       = (N_NODES + 31) / 32;       // 1563 gemm1 blocks (32 nodes)
constexpr int GSB      = (N_NODES + 255) / 256;     // 196 gstart blocks
constexpr int NB2      = 64;                        // nodes per gemm2_pool block

// Workspace layout in 4-byte units (~33.1 MB; 45.7 MB proven available).
constexpr size_t OFF_POOL  = 0;                                 // f32 [256*128]
constexpr size_t OFF_GST   = 32768;                             // i32 [257]
constexpr size_t OFF_BBASE = 33026;                             // i32 [197]
constexpr size_t OFF_DIS   = 33224;                             // f32 [50000]
constexpr size_t OFF_RS    = 83224;                             // i32 [50000]
constexpr size_t OFF_HCNT  = 133224;                            // i32 [782*196]
constexpr size_t OFF_REC   = 286496;                            // uint2 [800000]
constexpr size_t OFF_PART  = OFF_REC + 2 * (size_t)N_EDGES;     // uint4 [800000] (16B-aligned)
constexpr size_t OFF_H1    = OFF_PART;  // bf16x2 [50000*32]; overlays part (dead after P3)
constexpr size_t OFF_H1P   = OFF_PART + 4 * (size_t)N_EDGES;    // bf16x2 [50000*32]
constexpr size_t OFF_AGG2  = OFF_H1P;   // f32 [50000*64]; overlays h1p (dead after gather1)

// bf16 helpers: pack with round-to-nearest-even; unpack via shift.
__device__ inline unsigned bf16r(float f) {
    unsigned u = __float_as_uint(f);
    return (u + 0x7fffu + ((u >> 16) & 1u)) >> 16;
}
__device__ inline unsigned bf16pack2(float lo, float hi) {
    return bf16r(lo) | (bf16r(hi) << 16);
}
__device__ inline float bflo(unsigned v) { return __uint_as_float(v << 16); }
__device__ inline float bfhi(unsigned v) { return __uint_as_float(v & 0xffff0000u); }

__device__ inline void fma4(float4& acc, float s, const float4& v) {
    acc.x += s * v.x; acc.y += s * v.y; acc.z += s * v.z; acc.w += s * v.w;
}

// ---- P1: per-block bucket histogram (LDS atomics only) ----
__global__ __launch_bounds__(256) void k_p1(const int* __restrict__ dst,
                                            int* __restrict__ hcnt) {
    __shared__ int lh[NBKT];
    int tid = threadIdx.x;
    for (int i = tid; i < NBKT; i += 256) lh[i] = 0;
    __syncthreads();
    int base = blockIdx.x * 1024;
    #pragma unroll
    for (int j = 0; j < 4; ++j) {
        int e = base + j * 256 + tid;
        if (e < N_EDGES) atomicAdd(&lh[dst[e] >> 8], 1);
    }
    __syncthreads();
    for (int i = tid; i < NBKT; i += 256) hcnt[blockIdx.x * NBKT + i] = lh[i];
}

// ---- KAB: bucket totals + exclusive scan -> bbase[197] (one block) ----
__global__ __launch_bounds__(256) void k_kab(const int* __restrict__ hcnt,
                                             int* __restrict__ bbase) {
    __shared__ int tile[256];
    int t = threadIdx.x;
    int v = 0;
    if (t < NBKT) {
        for (int i = 0; i < EB; ++i) v += hcnt[i * NBKT + t];
    }
    tile[t] = v;
    __syncthreads();
    for (int off = 1; off < 256; off <<= 1) {
        int a = (t >= off) ? tile[t - off] : 0;
        __syncthreads();
        tile[t] += a;
        __syncthreads();
    }
    if (t < NBKT) bbase[t] = tile[t] - v;       // exclusive
    if (t == NBKT - 1) bbase[NBKT] = tile[t];   // total = N_EDGES
}

// ---- KC: per-bucket column scan of hcnt in place (+ gstart role) ----
__global__ __launch_bounds__(256) void k_kc(int* __restrict__ hcnt,
                                            const int* __restrict__ bbase,
                                            const int* __restrict__ batch,
                                            int* __restrict__ gstart) {
    __shared__ int tile[256];
    __shared__ int carry;
    int t = threadIdx.x;
    if (blockIdx.x < NBKT) {
        int b = blockIdx.x;
        if (t == 0) carry = bbase[b];
        __syncthreads();
        for (int i0 = 0; i0 < EB; i0 += 256) {
            int i = i0 + t;
            int v = (i < EB) ? hcnt[i * NBKT + b] : 0;
            tile[t] = v;
            __syncthreads();
            for (int off = 1; off < 256; off <<= 1) {
                int a = (t >= off) ? tile[t - off] : 0;
                __syncthreads();
                tile[t] += a;
                __syncthreads();
            }
            int incl = tile[t];
            if (i < EB) hcnt[i * NBKT + b] = carry + incl - v;   // exclusive + carry
            __syncthreads();
            if (t == 255) carry += incl;
            __syncthreads();
        }
        return;
    }
    // ---- gstart role: sorted-batch boundary detection ----
    int i = (blockIdx.x - NBKT) * 256 + t;
    if (i >= N_NODES) return;
    int g = batch[i];
    if (i == 0) {
        for (int gg = 0; gg <= g; ++gg) gstart[gg] = 0;
    } else {
        int gp = batch[i - 1];
        for (int gg = gp + 1; gg <= g; ++gg) gstart[gg] = i;
    }
    if (i == N_NODES - 1) {
        for (int gg = g + 1; gg <= N_GRAPHS; ++gg) gstart[gg] = N_NODES;
    }
}

// ---- P2: partition edges into buckets (LDS cursors, no global atomics) ----
__global__ __launch_bounds__(256) void k_p2(const int* __restrict__ src,
                                            const int* __restrict__ dst,
                                            const float* __restrict__ ew,
                                            const int* __restrict__ hcnt,
                                            uint4* __restrict__ part) {
    __shared__ int lb[NBKT];
    __shared__ int lc[NBKT];
    int tid = threadIdx.x;
    for (int i = tid; i < NBKT; i += 256) {
        lb[i] = hcnt[blockIdx.x * NBKT + i];
        lc[i] = 0;
    }
    __syncthreads();
    int base = blockIdx.x * 1024;
    #pragma unroll
    for (int j = 0; j < 4; ++j) {
        int e = base + j * 256 + tid;
        if (e < N_EDGES) {
            int d = dst[e];
            int b = d >> 8;
            int r = atomicAdd(&lc[b], 1);
            part[lb[b] + r] = make_uint4((unsigned)src[e], (unsigned)d,
                                         __float_as_uint(ew[e]), 0u);
        }
    }
}

// ---- P3 (+gemm1 het-fused): per-bucket CSR finalize + degree + dis ----
// blocks [0,NBKT): bucket b = 256 contiguous nodes; LDS count + f32 degree
// sum, block scan -> rs (end pointers), dis, LDS-cursor scatter -> rec.
// blocks [NBKT,NBKT+GB): h1p(bf16) = x @ W1; 32 nodes/block, thread =
// 2 nodes x 4 cols, k-vectorized b128 LDS reads.
__global__ __launch_bounds__(256) void k_p3_gemm1(const uint4* __restrict__ part,
                                                  const int* __restrict__ bbase,
                                                  int* __restrict__ rs,
                                                  float* __restrict__ dis,
                                                  uint2* __restrict__ rec,
                                                  const float* __restrict__ x,
                                                  const float* __restrict__ W1,
                                                  unsigned* __restrict__ h) {
    __shared__ float Ws[IN_DIM * HID];      // 32 KB (gemm role)
    __shared__ float xs[32][IN_DIM + 4];    // 16.5 KB, stride 132 -> conflict-free
    __shared__ int   cnt[256];
    __shared__ float dgw[256];
    __shared__ int   scn[256];
    __shared__ int   cur[256];
    int tid = threadIdx.x;
    if (blockIdx.x < NBKT) {
        int b = blockIdx.x;
        int base_node = b << 8;
        int ebeg = bbase[b], eend = bbase[b + 1];
        cnt[tid] = 0;
        dgw[tid] = 0.f;
        __syncthreads();
        for (int e = ebeg + tid; e < eend; e += 256) {
            uint4 r = part[e];
            int ld = (int)r.y & 255;
            atomicAdd(&cnt[ld], 1);
            atomicAdd(&dgw[ld], __uint_as_float(r.z));
        }
        __syncthreads();
        scn[tid] = cnt[tid];
        __syncthreads();
        for (int off = 1; off < 256; off <<= 1) {
            int a = (tid >= off) ? scn[tid - off] : 0;
            __syncthreads();
            scn[tid] += a;
            __syncthreads();
        }
        int node = base_node + tid;
        if (node < N_NODES) {
            rs[node] = ebeg + scn[tid];                 // end pointer
            dis[node] = rsqrtf(dgw[tid] + 1.0f);        // + self-loop weight 1
        }
        cur[tid] = ebeg + scn[tid] - cnt[tid];          // row start cursor
        __syncthreads();
        for (int e = ebeg + tid; e < eend; e += 256) {
            uint4 r = part[e];
            int ld = (int)r.y & 255;
            int pos = atomicAdd(&cur[ld], 1);
            rec[pos] = make_uint2(r.x, r.z);            // (src, ew_bits)
        }
        return;
    }
    // ---- gemm1 role ----
    int bid = blockIdx.x - NBKT;
    const float4* W4 = (const float4*)W1;
    float4* Ws4 = (float4*)Ws;
    for (int i = tid; i < IN_DIM * HID / 4; i += 256) Ws4[i] = W4[i];
    int base = bid * 32;
    const float4* X4 = (const float4*)x;
    for (int i = tid; i < 32 * 32; i += 256) {           // 32 rows x 32 float4
        int ln = i >> 5, kq = i & 31;
        int node = base + ln;
        float4 v = (node < N_NODES) ? X4[(size_t)node * 32 + kq]
                                    : make_float4(0.f, 0.f, 0.f, 0.f);
        *(float4*)&xs[ln][kq * 4] = v;
    }
    __syncthreads();
    int np = tid >> 4;            // node pair 0..15
    int q  = tid & 15;            // col quad 0..15
    int n0 = np * 2, n1 = n0 + 1;
    float4 a0 = make_float4(0.f, 0.f, 0.f, 0.f);
    float4 a1 = a0;
    #pragma unroll 4
    for (int k4 = 0; k4 < IN_DIM; k4 += 4) {
        float4 xv0 = *(const float4*)&xs[n0][k4];
        float4 xv1 = *(const float4*)&xs[n1][k4];
        float4 w0 = Ws4[(k4 + 0) * 16 + q];
        float4 w1 = Ws4[(k4 + 1) * 16 + q];
        float4 w2 = Ws4[(k4 + 2) * 16 + q];
        float4 w3 = Ws4[(k4 + 3) * 16 + q];
        fma4(a0, xv0.x, w0); fma4(a0, xv0.y, w1); fma4(a0, xv0.z, w2); fma4(a0, xv0.w, w3);
        fma4(a1, xv1.x, w0); fma4(a1, xv1.y, w1); fma4(a1, xv1.z, w2); fma4(a1, xv1.w, w3);
    }
    int nd0 = base + n0, nd1 = base + n1;
    if (nd0 < N_NODES) {
        uint2 p = make_uint2(bf16pack2(a0.x, a0.y), bf16pack2(a0.z, a0.w));
        ((uint2*)h)[(size_t)nd0 * 16 + q] = p;
    }
    if (nd1 < N_NODES) {
        uint2 p = make_uint2(bf16pack2(a1.x, a1.y), bf16pack2(a1.z, a1.w));
        ((uint2*)h)[(size_t)nd1 * 16 + q] = p;
    }
}

// ---- 64-dim CSR gather over bf16 table: ----
// out[n] = dis[n]*(sum_e dis[s]*ew*T[s] + dis[n]*T[n]) (+bias,relu)
// One wave per node; halves interleave records; 4 records/half in flight.
// T rows: 32 u32, each = 2 bf16 cols. Output bf16 (h1) or f32 (agg2).
template <bool RELU_BIAS, bool OUT_BF16>
__global__ __launch_bounds__(256) void k_gather64(const uint2* __restrict__ rec,
                                                  const int* __restrict__ rs,
                                                  const float* __restrict__ dis,
                                                  const unsigned* __restrict__ T,
                                                  const float* __restrict__ bias,
                                                  void* __restrict__ outv) {
    int wave = (blockIdx.x * 256 + threadIdx.x) >> 6;
    int lane = threadIdx.x & 63;
    int half = lane >> 5;
    int l    = lane & 31;         // col-pair index within row
    if (wave >= N_NODES) return;
    int n = wave;
    int begin = (n == 0) ? 0 : rs[n - 1];
    int end = rs[n];

    float ax0 = 0.f, ay0 = 0.f, ax1 = 0.f, ay1 = 0.f;
    float ax2 = 0.f, ay2 = 0.f, ax3 = 0.f, ay3 = 0.f;
    int k = begin + half;
    while (k + 6 < end) {                   // 4 records per half per iter
        uint2 r0 = rec[k];
        uint2 r1 = rec[k + 2];
        uint2 r2 = rec[k + 4];
        uint2 r3 = rec[k + 6];
        float d0 = dis[r0.x];
        float d1 = dis[r1.x];
        float d2 = dis[r2.x];
        float d3 = dis[r3.x];
        unsigned t0 = T[(size_t)r0.x * 32 + l];
        unsigned t1 = T[(size_t)r1.x * 32 + l];
        unsigned t2 = T[(size_t)r2.x * 32 + l];
        unsigned t3 = T[(size_t)r3.x * 32 + l];
        float n0 = d0 * __uint_as_float(r0.y);
        float n1 = d1 * __uint_as_float(r1.y);
        float n2 = d2 * __uint_as_float(r2.y);
        float n3 = d3 * __uint_as_float(r3.y);
        ax0 += bflo(t0) * n0; ay0 += bfhi(t0) * n0;
        ax1 += bflo(t1) * n1; ay1 += bfhi(t1) * n1;
        ax2 += bflo(t2) * n2; ay2 += bfhi(t2) * n2;
        ax3 += bflo(t3) * n3; ay3 += bfhi(t3) * n3;
        k += 8;
    }
    while (k < end) {                       // remainder
        uint2 r = rec[k];
        float nn = dis[r.x] * __uint_as_float(r.y);
        unsigned t = T[(size_t)r.x * 32 + l];
        ax0 += bflo(t) * nn; ay0 += bfhi(t) * nn;
        k += 2;
    }
    float ax = (ax0 + ax1) + (ax2 + ax3);
    float ay = (ay0 + ay1) + (ay2 + ay3);
    float di = dis[n];
    if (half == 0) {                        // self-loop (pre-factored form)
        unsigned t = T[(size_t)n * 32 + l];
        ax += bflo(t) * di; ay += bfhi(t) * di;
    }
    ax += __shfl_xor(ax, 32, 64);           // combine halves
    ay += __shfl_xor(ay, 32, 64);
    if (half == 0) {
        ax *= di; ay *= di;                 // wave-uniform dis[n] factor
        if (RELU_BIAS) {
            const float2* B2 = (const float2*)bias;
            float2 b = B2[l];
            ax += b.x; ay += b.y;
            ax = ax > 0.f ? ax : 0.f;
            ay = ay > 0.f ? ay : 0.f;
        }
        if (OUT_BF16) {
            ((unsigned*)outv)[(size_t)n * 32 + l] = bf16pack2(ax, ay);
        } else {
            ((float2*)outv)[(size_t)n * 32 + l] = make_float2(ax, ay);
        }
    }
}

// ---- fused: h2 = relu(agg2 @ W2 + b2); pool[batch] += h2 (run-length) ----
__global__ __launch_bounds__(256) void k_gemm2_pool(const float* __restrict__ agg,
                                                    const float* __restrict__ W2,
                                                    const float* __restrict__ b2,
                                                    const int* __restrict__ batch,
                                                    float* __restrict__ pool) {
    __shared__ float Ws[HID * EMB];         // 32 KB
    __shared__ float as[NB2][HID];          // 16 KB (broadcast reads)
    __shared__ int   bs[NB2];
    int tid = threadIdx.x;
    const float4* W4 = (const float4*)W2;
    float4* Ws4 = (float4*)Ws;
    for (int i = tid; i < HID * EMB / 4; i += 256) Ws4[i] = W4[i];
    int base = blockIdx.x * NB2;
    const float4* A4 = (const float4*)agg;
    float4* as4 = (float4*)as;
    for (int i = tid; i < NB2 * HID / 4; i += 256) {
        int node = base + (i >> 4);
        as4[i] = (node < N_NODES) ? A4[(size_t)node * 16 + (i & 15)]
                                  : make_float4(0.f, 0.f, 0.f, 0.f);
    }
    if (tid < NB2) {
        int node = base + tid;
        bs[tid] = (node < N_NODES) ? batch[node] : -1;
    }
    __syncthreads();

    int c = tid & 31;
    int s = tid >> 5;
    int jc = c * 4;
    float4 bq = *(const float4*)&b2[jc];
    float4 racc = make_float4(0.f, 0.f, 0.f, 0.f);
    int gcur = -1;
    for (int ni = s * 8; ni < s * 8 + 8; ++ni) {
        int g = bs[ni];
        if (g != gcur) {
            if (gcur >= 0) {
                float* p = &pool[(size_t)gcur * EMB + jc];
                atomicAdd(p + 0, racc.x); atomicAdd(p + 1, racc.y);
                atomicAdd(p + 2, racc.z); atomicAdd(p + 3, racc.w);
            }
            racc = make_float4(0.f, 0.f, 0.f, 0.f);
            gcur = g;
        }
        if (g < 0) continue;
        float4 acc = bq;
        #pragma unroll 8
        for (int k = 0; k < HID; ++k) {
            float a = as[ni][k];
            float4 w = Ws4[k * 32 + c];
            acc.x += a * w.x; acc.y += a * w.y; acc.z += a * w.z; acc.w += a * w.w;
        }
        racc.x += fmaxf(acc.x, 0.f);
        racc.y += fmaxf(acc.y, 0.f);
        racc.z += fmaxf(acc.z, 0.f);
        racc.w += fmaxf(acc.w, 0.f);
    }
    if (gcur >= 0) {
        float* p = &pool[(size_t)gcur * EMB + jc];
        atomicAdd(p + 0, racc.x); atomicAdd(p + 1, racc.y);
        atomicAdd(p + 2, racc.z); atomicAdd(p + 3, racc.w);
    }
}

__global__ void k_divide(const float* __restrict__ pool, const int* __restrict__ gstart,
                         float* __restrict__ out) {
    int idx = blockIdx.x * blockDim.x + threadIdx.x;
    if (idx >= N_GRAPHS * EMB) return;
    int g = idx >> 7;
    float c = (float)(gstart[g + 1] - gstart[g]);
    out[idx] = pool[idx] / fmaxf(c, 1.0f);
}

extern "C" void kernel_launch(void* const* d_in, const int* in_sizes, int n_in,
                              void* d_out, int out_size, void* d_ws, size_t ws_size,
                              hipStream_t stream) {
    const float* x     = (const float*)d_in[0];
    const int*   eidx  = (const int*)d_in[1];     // [2, E]: src then dst
    const float* ew    = (const float*)d_in[2];
    const int*   batch = (const int*)d_in[3];
    const float* W1    = (const float*)d_in[4];
    const float* b1    = (const float*)d_in[5];
    const float* W2    = (const float*)d_in[6];
    const float* b2    = (const float*)d_in[7];
    float* out = (float*)d_out;

    const int* src = eidx;
    const int* dst = eidx + N_EDGES;

    float* ws     = (float*)d_ws;
    float* pool   = ws + OFF_POOL;
    int*   gstart = (int*)(ws + OFF_GST);
    int*   bbase  = (int*)(ws + OFF_BBASE);
    float* dis    = ws + OFF_DIS;
    int*   rs     = (int*)(ws + OFF_RS);
    int*   hcnt   = (int*)(ws + OFF_HCNT);
    uint2* rec    = (uint2*)(ws + OFF_REC);
    uint4* part   = (uint4*)(ws + OFF_PART);
    unsigned* h1  = (unsigned*)(ws + OFF_H1);   // bf16x2; overlays part (dead after P3)
    unsigned* h1p = (unsigned*)(ws + OFF_H1P);  // bf16x2
    float* agg2   = ws + OFF_AGG2;              // f32; overlays h1p (dead after gather1)

    // Only pool needs zeroing (everything else fully written).
    (void)hipMemsetAsync(pool, 0, (size_t)N_GRAPHS * EMB * sizeof(float), stream);

    // Bucket counting sort (no global atomics anywhere).
    k_p1<<<EB, 256, 0, stream>>>(dst, hcnt);
    k_kab<<<1, 256, 0, stream>>>(hcnt, bbase);
    k_kc<<<NBKT + GSB, 256, 0, stream>>>(hcnt, bbase, batch, gstart);
    k_p2<<<EB, 256, 0, stream>>>(src, dst, ew, hcnt, part);

    // Per-bucket CSR finalize + degree/dis, het-fused with layer-1 linear.
    k_p3_gemm1<<<NBKT + GB, 256, 0, stream>>>(part, bbase, rs, dis, rec, x, W1, h1p);

    // Layer 1 aggregate + bias + relu: bf16 table -> bf16 h1.
    k_gather64<true, true><<<N_NODES / 4, 256, 0, stream>>>(rec, rs, dis, h1p, b1, h1);

    // Layer 2 aggregate BEFORE the linear: bf16 h1 -> f32 agg2.
    k_gather64<false, false><<<N_NODES / 4, 256, 0, stream>>>(rec, rs, dis, h1, nullptr, agg2);

    // Fused layer-2 linear + relu + run-length pooled accumulate.
    k_gemm2_pool<<<(N_NODES + NB2 - 1) / NB2, 256, 0, stream>>>(agg2, W2, b2, batch, pool);

    k_divide<<<(N_GRAPHS * EMB + 255) / 256, 256, 0, stream>>>(pool, gstart, out);
}

// Round 10
// 252.098 us; speedup vs baseline: 3.8987x; 1.0311x over previous
//
#include <hip/hip_runtime.h>

// GCNEncoder round 10: round-9 pipeline + gemm2_pool loop interchange.
// The 45us gemm2_pool was LDS-instruction-bound (1024 LDS instr / 2048 FMA
// per thread: w re-read per node). k-outer / node-inner with 8 live node
// accumulators cuts LDS instr to 192/thread (w read once per k4).
constexpr int N_NODES  = 50000;
constexpr int N_EDGES  = 800000;
constexpr int N_GRAPHS = 256;
constexpr int IN_DIM   = 128;
constexpr int HID      = 64;
constexpr int EMB      = 128;
constexpr int NBKT     = 196;                       // buckets: dst>>8
constexpr int EB       = (N_EDGES + 1023) / 1024;   // 782 edge blocks
constexpr int GB       = (N_NODES + 31) / 32;       // 1563 gemm1 blocks (32 nodes)
constexpr int GSB      = (N_NODES + 255) / 256;     // 196 gstart blocks
constexpr int NB2      = 64;                        // nodes per gemm2_pool block

// Workspace layout in 4-byte units (~33.1 MB; 45.7 MB proven available).
constexpr size_t OFF_POOL  = 0;                                 // f32 [256*128]
constexpr size_t OFF_GST   = 32768;                             // i32 [257]
constexpr size_t OFF_BBASE = 33026;                             // i32 [197]
constexpr size_t OFF_DIS   = 33224;                             // f32 [50000]
constexpr size_t OFF_RS    = 83224;                             // i32 [50000]
constexpr size_t OFF_HCNT  = 133224;                            // i32 [782*196]
constexpr size_t OFF_REC   = 286496;                            // uint2 [800000]
constexpr size_t OFF_PART  = OFF_REC + 2 * (size_t)N_EDGES;     // uint4 [800000] (16B-aligned)
constexpr size_t OFF_H1    = OFF_PART;  // bf16x2 [50000*32]; overlays part (dead after P3)
constexpr size_t OFF_H1P   = OFF_PART + 4 * (size_t)N_EDGES;    // bf16x2 [50000*32]
constexpr size_t OFF_AGG2  = OFF_H1P;   // f32 [50000*64]; overlays h1p (dead after gather1)

// bf16 helpers: pack with round-to-nearest-even; unpack via shift.
__device__ inline unsigned bf16r(float f) {
    unsigned u = __float_as_uint(f);
    return (u + 0x7fffu + ((u >> 16) & 1u)) >> 16;
}
__device__ inline unsigned bf16pack2(float lo, float hi) {
    return bf16r(lo) | (bf16r(hi) << 16);
}
__device__ inline float bflo(unsigned v) { return __uint_as_float(v << 16); }
__device__ inline float bfhi(unsigned v) { return __uint_as_float(v & 0xffff0000u); }

__device__ inline void fma4(float4& acc, float s, const float4& v) {
    acc.x += s * v.x; acc.y += s * v.y; acc.z += s * v.z; acc.w += s * v.w;
}

// ---- P1: per-block bucket histogram (LDS atomics only) ----
__global__ __launch_bounds__(256) void k_p1(const int* __restrict__ dst,
                                            int* __restrict__ hcnt) {
    __shared__ int lh[NBKT];
    int tid = threadIdx.x;
    for (int i = tid; i < NBKT; i += 256) lh[i] = 0;
    __syncthreads();
    int base = blockIdx.x * 1024;
    #pragma unroll
    for (int j = 0; j < 4; ++j) {
        int e = base + j * 256 + tid;
        if (e < N_EDGES) atomicAdd(&lh[dst[e] >> 8], 1);
    }
    __syncthreads();
    for (int i = tid; i < NBKT; i += 256) hcnt[blockIdx.x * NBKT + i] = lh[i];
}

// ---- KAB: bucket totals + exclusive scan -> bbase[197] (one block) ----
__global__ __launch_bounds__(256) void k_kab(const int* __restrict__ hcnt,
                                             int* __restrict__ bbase) {
    __shared__ int tile[256];
    int t = threadIdx.x;
    int v = 0;
    if (t < NBKT) {
        for (int i = 0; i < EB; ++i) v += hcnt[i * NBKT + t];
    }
    tile[t] = v;
    __syncthreads();
    for (int off = 1; off < 256; off <<= 1) {
        int a = (t >= off) ? tile[t - off] : 0;
        __syncthreads();
        tile[t] += a;
        __syncthreads();
    }
    if (t < NBKT) bbase[t] = tile[t] - v;       // exclusive
    if (t == NBKT - 1) bbase[NBKT] = tile[t];   // total = N_EDGES
}

// ---- KC: per-bucket column scan of hcnt in place (+ gstart role) ----
__global__ __launch_bounds__(256) void k_kc(int* __restrict__ hcnt,
                                            const int* __restrict__ bbase,
                                            const int* __restrict__ batch,
                                            int* __restrict__ gstart) {
    __shared__ int tile[256];
    __shared__ int carry;
    int t = threadIdx.x;
    if (blockIdx.x < NBKT) {
        int b = blockIdx.x;
        if (t == 0) carry = bbase[b];
        __syncthreads();
        for (int i0 = 0; i0 < EB; i0 += 256) {
            int i = i0 + t;
            int v = (i < EB) ? hcnt[i * NBKT + b] : 0;
            tile[t] = v;
            __syncthreads();
            for (int off = 1; off < 256; off <<= 1) {
                int a = (t >= off) ? tile[t - off] : 0;
                __syncthreads();
                tile[t] += a;
                __syncthreads();
            }
            int incl = tile[t];
            if (i < EB) hcnt[i * NBKT + b] = carry + incl - v;   // exclusive + carry
            __syncthreads();
            if (t == 255) carry += incl;
            __syncthreads();
        }
        return;
    }
    // ---- gstart role: sorted-batch boundary detection ----
    int i = (blockIdx.x - NBKT) * 256 + t;
    if (i >= N_NODES) return;
    int g = batch[i];
    if (i == 0) {
        for (int gg = 0; gg <= g; ++gg) gstart[gg] = 0;
    } else {
        int gp = batch[i - 1];
        for (int gg = gp + 1; gg <= g; ++gg) gstart[gg] = i;
    }
    if (i == N_NODES - 1) {
        for (int gg = g + 1; gg <= N_GRAPHS; ++gg) gstart[gg] = N_NODES;
    }
}

// ---- P2: partition edges into buckets (LDS cursors, no global atomics) ----
__global__ __launch_bounds__(256) void k_p2(const int* __restrict__ src,
                                            const int* __restrict__ dst,
                                            const float* __restrict__ ew,
                                            const int* __restrict__ hcnt,
                                            uint4* __restrict__ part) {
    __shared__ int lb[NBKT];
    __shared__ int lc[NBKT];
    int tid = threadIdx.x;
    for (int i = tid; i < NBKT; i += 256) {
        lb[i] = hcnt[blockIdx.x * NBKT + i];
        lc[i] = 0;
    }
    __syncthreads();
    int base = blockIdx.x * 1024;
    #pragma unroll
    for (int j = 0; j < 4; ++j) {
        int e = base + j * 256 + tid;
        if (e < N_EDGES) {
            int d = dst[e];
            int b = d >> 8;
            int r = atomicAdd(&lc[b], 1);
            part[lb[b] + r] = make_uint4((unsigned)src[e], (unsigned)d,
                                         __float_as_uint(ew[e]), 0u);
        }
    }
}

// ---- P3 (+gemm1 het-fused): per-bucket CSR finalize + degree + dis ----
__global__ __launch_bounds__(256) void k_p3_gemm1(const uint4* __restrict__ part,
                                                  const int* __restrict__ bbase,
                                                  int* __restrict__ rs,
                                                  float* __restrict__ dis,
                                                  uint2* __restrict__ rec,
                                                  const float* __restrict__ x,
                                                  const float* __restrict__ W1,
                                                  unsigned* __restrict__ h) {
    __shared__ float Ws[IN_DIM * HID];      // 32 KB (gemm role)
    __shared__ float xs[32][IN_DIM + 4];    // 16.5 KB, stride 132 -> conflict-free
    __shared__ int   cnt[256];
    __shared__ float dgw[256];
    __shared__ int   scn[256];
    __shared__ int   cur[256];
    int tid = threadIdx.x;
    if (blockIdx.x < NBKT) {
        int b = blockIdx.x;
        int base_node = b << 8;
        int ebeg = bbase[b], eend = bbase[b + 1];
        cnt[tid] = 0;
        dgw[tid] = 0.f;
        __syncthreads();
        for (int e = ebeg + tid; e < eend; e += 256) {
            uint4 r = part[e];
            int ld = (int)r.y & 255;
            atomicAdd(&cnt[ld], 1);
            atomicAdd(&dgw[ld], __uint_as_float(r.z));
        }
        __syncthreads();
        scn[tid] = cnt[tid];
        __syncthreads();
        for (int off = 1; off < 256; off <<= 1) {
            int a = (tid >= off) ? scn[tid - off] : 0;
            __syncthreads();
            scn[tid] += a;
            __syncthreads();
        }
        int node = base_node + tid;
        if (node < N_NODES) {
            rs[node] = ebeg + scn[tid];                 // end pointer
            dis[node] = rsqrtf(dgw[tid] + 1.0f);        // + self-loop weight 1
        }
        cur[tid] = ebeg + scn[tid] - cnt[tid];          // row start cursor
        __syncthreads();
        for (int e = ebeg + tid; e < eend; e += 256) {
            uint4 r = part[e];
            int ld = (int)r.y & 255;
            int pos = atomicAdd(&cur[ld], 1);
            rec[pos] = make_uint2(r.x, r.z);            // (src, ew_bits)
        }
        return;
    }
    // ---- gemm1 role: 32 nodes/block, thread = 2 nodes x 4 cols ----
    int bid = blockIdx.x - NBKT;
    const float4* W4 = (const float4*)W1;
    float4* Ws4 = (float4*)Ws;
    for (int i = tid; i < IN_DIM * HID / 4; i += 256) Ws4[i] = W4[i];
    int base = bid * 32;
    const float4* X4 = (const float4*)x;
    for (int i = tid; i < 32 * 32; i += 256) {           // 32 rows x 32 float4
        int ln = i >> 5, kq = i & 31;
        int node = base + ln;
        float4 v = (node < N_NODES) ? X4[(size_t)node * 32 + kq]
                                    : make_float4(0.f, 0.f, 0.f, 0.f);
        *(float4*)&xs[ln][kq * 4] = v;
    }
    __syncthreads();
    int np = tid >> 4;            // node pair 0..15
    int q  = tid & 15;            // col quad 0..15
    int n0 = np * 2, n1 = n0 + 1;
    float4 a0 = make_float4(0.f, 0.f, 0.f, 0.f);
    float4 a1 = a0;
    #pragma unroll 4
    for (int k4 = 0; k4 < IN_DIM; k4 += 4) {
        float4 xv0 = *(const float4*)&xs[n0][k4];
        float4 xv1 = *(const float4*)&xs[n1][k4];
        float4 w0 = Ws4[(k4 + 0) * 16 + q];
        float4 w1 = Ws4[(k4 + 1) * 16 + q];
        float4 w2 = Ws4[(k4 + 2) * 16 + q];
        float4 w3 = Ws4[(k4 + 3) * 16 + q];
        fma4(a0, xv0.x, w0); fma4(a0, xv0.y, w1); fma4(a0, xv0.z, w2); fma4(a0, xv0.w, w3);
        fma4(a1, xv1.x, w0); fma4(a1, xv1.y, w1); fma4(a1, xv1.z, w2); fma4(a1, xv1.w, w3);
    }
    int nd0 = base + n0, nd1 = base + n1;
    if (nd0 < N_NODES) {
        uint2 p = make_uint2(bf16pack2(a0.x, a0.y), bf16pack2(a0.z, a0.w));
        ((uint2*)h)[(size_t)nd0 * 16 + q] = p;
    }
    if (nd1 < N_NODES) {
        uint2 p = make_uint2(bf16pack2(a1.x, a1.y), bf16pack2(a1.z, a1.w));
        ((uint2*)h)[(size_t)nd1 * 16 + q] = p;
    }
}

// ---- 64-dim CSR gather over bf16 table ----
template <bool RELU_BIAS, bool OUT_BF16>
__global__ __launch_bounds__(256) void k_gather64(const uint2* __restrict__ rec,
                                                  const int* __restrict__ rs,
                                                  const float* __restrict__ dis,
                                                  const unsigned* __restrict__ T,
                                                  const float* __restrict__ bias,
                                                  void* __restrict__ outv) {
    int wave = (blockIdx.x * 256 + threadIdx.x) >> 6;
    int lane = threadIdx.x & 63;
    int half = lane >> 5;
    int l    = lane & 31;         // col-pair index within row
    if (wave >= N_NODES) return;
    int n = wave;
    int begin = (n == 0) ? 0 : rs[n - 1];
    int end = rs[n];

    float ax0 = 0.f, ay0 = 0.f, ax1 = 0.f, ay1 = 0.f;
    float ax2 = 0.f, ay2 = 0.f, ax3 = 0.f, ay3 = 0.f;
    int k = begin + half;
    while (k + 6 < end) {                   // 4 records per half per iter
        uint2 r0 = rec[k];
        uint2 r1 = rec[k + 2];
        uint2 r2 = rec[k + 4];
        uint2 r3 = rec[k + 6];
        float d0 = dis[r0.x];
        float d1 = dis[r1.x];
        float d2 = dis[r2.x];
        float d3 = dis[r3.x];
        unsigned t0 = T[(size_t)r0.x * 32 + l];
        unsigned t1 = T[(size_t)r1.x * 32 + l];
        unsigned t2 = T[(size_t)r2.x * 32 + l];
        unsigned t3 = T[(size_t)r3.x * 32 + l];
        float n0 = d0 * __uint_as_float(r0.y);
        float n1 = d1 * __uint_as_float(r1.y);
        float n2 = d2 * __uint_as_float(r2.y);
        float n3 = d3 * __uint_as_float(r3.y);
        ax0 += bflo(t0) * n0; ay0 += bfhi(t0) * n0;
        ax1 += bflo(t1) * n1; ay1 += bfhi(t1) * n1;
        ax2 += bflo(t2) * n2; ay2 += bfhi(t2) * n2;
        ax3 += bflo(t3) * n3; ay3 += bfhi(t3) * n3;
        k += 8;
    }
    while (k < end) {                       // remainder
        uint2 r = rec[k];
        float nn = dis[r.x] * __uint_as_float(r.y);
        unsigned t = T[(size_t)r.x * 32 + l];
        ax0 += bflo(t) * nn; ay0 += bfhi(t) * nn;
        k += 2;
    }
    float ax = (ax0 + ax1) + (ax2 + ax3);
    float ay = (ay0 + ay1) + (ay2 + ay3);
    float di = dis[n];
    if (half == 0) {                        // self-loop (pre-factored form)
        unsigned t = T[(size_t)n * 32 + l];
        ax += bflo(t) * di; ay += bfhi(t) * di;
    }
    ax += __shfl_xor(ax, 32, 64);           // combine halves
    ay += __shfl_xor(ay, 32, 64);
    if (half == 0) {
        ax *= di; ay *= di;                 // wave-uniform dis[n] factor
        if (RELU_BIAS) {
            const float2* B2 = (const float2*)bias;
            float2 b = B2[l];
            ax += b.x; ay += b.y;
            ax = ax > 0.f ? ax : 0.f;
            ay = ay > 0.f ? ay : 0.f;
        }
        if (OUT_BF16) {
            ((unsigned*)outv)[(size_t)n * 32 + l] = bf16pack2(ax, ay);
        } else {
            ((float2*)outv)[(size_t)n * 32 + l] = make_float2(ax, ay);
        }
    }
}

// ---- fused: h2 = relu(agg2 @ W2 + b2); pool[batch] += h2 (run-length) ----
// k-outer / node-inner: w float4s read ONCE per k4 and applied to all 8
// nodes (32 live accumulators). 192 LDS instr / 2048 FMA per thread
// (was 1024/2048 -> LDS-pipe-bound at 45us).
__global__ __launch_bounds__(256) void k_gemm2_pool(const float* __restrict__ agg,
                                                    const float* __restrict__ W2,
                                                    const float* __restrict__ b2,
                                                    const int* __restrict__ batch,
                                                    float* __restrict__ pool) {
    __shared__ float Ws[HID * EMB];         // 32 KB
    __shared__ float as[NB2][HID];          // 16 KB (broadcast reads)
    __shared__ int   bs[NB2];
    int tid = threadIdx.x;
    const float4* W4 = (const float4*)W2;
    float4* Ws4 = (float4*)Ws;
    for (int i = tid; i < HID * EMB / 4; i += 256) Ws4[i] = W4[i];
    int base = blockIdx.x * NB2;
    const float4* A4 = (const float4*)agg;
    float4* as4 = (float4*)as;
    for (int i = tid; i < NB2 * HID / 4; i += 256) {
        int node = base + (i >> 4);
        as4[i] = (node < N_NODES) ? A4[(size_t)node * 16 + (i & 15)]
                                  : make_float4(0.f, 0.f, 0.f, 0.f);
    }
    if (tid < NB2) {
        int node = base + tid;
        bs[tid] = (node < N_NODES) ? batch[node] : -1;
    }
    __syncthreads();

    int c = tid & 31;             // column-quad id (4 cols)
    int s = tid >> 5;             // node slice 0..7 (8 contiguous nodes)
    int jc = c * 4;
    int nb = s * 8;
    float4 acc[8];
    #pragma unroll
    for (int i = 0; i < 8; ++i) acc[i] = make_float4(0.f, 0.f, 0.f, 0.f);
    #pragma unroll 4
    for (int k4 = 0; k4 < HID; k4 += 4) {
        float4 w0 = Ws4[(k4 + 0) * 32 + c];
        float4 w1 = Ws4[(k4 + 1) * 32 + c];
        float4 w2 = Ws4[(k4 + 2) * 32 + c];
        float4 w3 = Ws4[(k4 + 3) * 32 + c];
        #pragma unroll
        for (int i = 0; i < 8; ++i) {
            float4 av = *(const float4*)&as[nb + i][k4];
            fma4(acc[i], av.x, w0); fma4(acc[i], av.y, w1);
            fma4(acc[i], av.z, w2); fma4(acc[i], av.w, w3);
        }
    }
    // Epilogue: bias + relu + run-length pooled accumulate (batch sorted).
    float4 bq = *(const float4*)&b2[jc];
    float4 racc = make_float4(0.f, 0.f, 0.f, 0.f);
    int gcur = -1;
    #pragma unroll
    for (int i = 0; i < 8; ++i) {
        int g = bs[nb + i];
        if (g != gcur) {
            if (gcur >= 0) {
                float* p = &pool[(size_t)gcur * EMB + jc];
                atomicAdd(p + 0, racc.x); atomicAdd(p + 1, racc.y);
                atomicAdd(p + 2, racc.z); atomicAdd(p + 3, racc.w);
            }
            racc = make_float4(0.f, 0.f, 0.f, 0.f);
            gcur = g;
        }
        if (g < 0) continue;
        racc.x += fmaxf(acc[i].x + bq.x, 0.f);
        racc.y += fmaxf(acc[i].y + bq.y, 0.f);
        racc.z += fmaxf(acc[i].z + bq.z, 0.f);
        racc.w += fmaxf(acc[i].w + bq.w, 0.f);
    }
    if (gcur >= 0) {
        float* p = &pool[(size_t)gcur * EMB + jc];
        atomicAdd(p + 0, racc.x); atomicAdd(p + 1, racc.y);
        atomicAdd(p + 2, racc.z); atomicAdd(p + 3, racc.w);
    }
}

__global__ void k_divide(const float* __restrict__ pool, const int* __restrict__ gstart,
                         float* __restrict__ out) {
    int idx = blockIdx.x * blockDim.x + threadIdx.x;
    if (idx >= N_GRAPHS * EMB) return;
    int g = idx >> 7;
    float c = (float)(gstart[g + 1] - gstart[g]);
    out[idx] = pool[idx] / fmaxf(c, 1.0f);
}

extern "C" void kernel_launch(void* const* d_in, const int* in_sizes, int n_in,
                              void* d_out, int out_size, void* d_ws, size_t ws_size,
                              hipStream_t stream) {
    const float* x     = (const float*)d_in[0];
    const int*   eidx  = (const int*)d_in[1];     // [2, E]: src then dst
    const float* ew    = (const float*)d_in[2];
    const int*   batch = (const int*)d_in[3];
    const float* W1    = (const float*)d_in[4];
    const float* b1    = (const float*)d_in[5];
    const float* W2    = (const float*)d_in[6];
    const float* b2    = (const float*)d_in[7];
    float* out = (float*)d_out;

    const int* src = eidx;
    const int* dst = eidx + N_EDGES;

    float* ws     = (float*)d_ws;
    float* pool   = ws + OFF_POOL;
    int*   gstart = (int*)(ws + OFF_GST);
    int*   bbase  = (int*)(ws + OFF_BBASE);
    float* dis    = ws + OFF_DIS;
    int*   rs     = (int*)(ws + OFF_RS);
    int*   hcnt   = (int*)(ws + OFF_HCNT);
    uint2* rec    = (uint2*)(ws + OFF_REC);
    uint4* part   = (uint4*)(ws + OFF_PART);
    unsigned* h1  = (unsigned*)(ws + OFF_H1);   // bf16x2; overlays part (dead after P3)
    unsigned* h1p = (unsigned*)(ws + OFF_H1P);  // bf16x2
    float* agg2   = ws + OFF_AGG2;              // f32; overlays h1p (dead after gather1)

    // Only pool needs zeroing (everything else fully written).
    (void)hipMemsetAsync(pool, 0, (size_t)N_GRAPHS * EMB * sizeof(float), stream);

    // Bucket counting sort (no global atomics anywhere).
    k_p1<<<EB, 256, 0, stream>>>(dst, hcnt);
    k_kab<<<1, 256, 0, stream>>>(hcnt, bbase);
    k_kc<<<NBKT + GSB, 256, 0, stream>>>(hcnt, bbase, batch, gstart);
    k_p2<<<EB, 256, 0, stream>>>(src, dst, ew, hcnt, part);

    // Per-bucket CSR finalize + degree/dis, het-fused with layer-1 linear.
    k_p3_gemm1<<<NBKT + GB, 256, 0, stream>>>(part, bbase, rs, dis, rec, x, W1, h1p);

    // Layer 1 aggregate + bias + relu: bf16 table -> bf16 h1.
    k_gather64<true, true><<<N_NODES / 4, 256, 0, stream>>>(rec, rs, dis, h1p, b1, h1);

    // Layer 2 aggregate BEFORE the linear: bf16 h1 -> f32 agg2.
    k_gather64<false, false><<<N_NODES / 4, 256, 0, stream>>>(rec, rs, dis, h1, nullptr, agg2);

    // Fused layer-2 linear + relu + run-length pooled accumulate.
    k_gemm2_pool<<<(N_NODES + NB2 - 1) / NB2, 256, 0, stream>>>(agg2, W2, b2, batch, pool);

    k_divide<<<(N_GRAPHS * EMB + 255) / 256, 256, 0, stream>>>(pool, gstart, out);
}